// Round 11
// baseline (2525.807 us; speedup 1.0000x reference)
//
#include <hip/hip_runtime.h>
#include <math.h>

#define T_TOTAL 262144
#define HID 32
#define WIN 3072                      /* windows: 85-86 serial steps each */
/* window geometry: first 1024 windows have 86 steps, rest 85.
   S(w) = 85*w + min(w,1024); contiguous, covers [0, 262144). */
#define NSWEEP 6                      /* total sweeps; NSWEEP-1 corrections */
#define CH 1024                       /* correction chunk size (3 chunks) */
#define FD_EPS0 4.0                   /* FD perturbation on s0 (snow) */
#define FD_EPS1 8.0                   /* FD perturbation on s1 (water) */
#define LOG2E 1.4426950408889634f
#define TANH2C 2.8853900817779268f    /* 2*log2e */
#define NEG10LOG2E (-14.426950408889634f)
#define POS10LOG2E (14.426950408889634f)

#define PIN(x) asm volatile("" : "+v"(x))

typedef _Float16 f16x8 __attribute__((ext_vector_type(8)));
typedef float f32x4 __attribute__((ext_vector_type(4)));

__device__ __forceinline__ float fexp2(float x) { return __builtin_amdgcn_exp2f(x); }
__device__ __forceinline__ float frcp(float x)  { return __builtin_amdgcn_rcpf(x); }
__device__ __forceinline__ float fast_sig10(float x) {
    return frcp(1.0f + fexp2(x * NEG10LOG2E));
}
__device__ __forceinline__ float fast_tanh_clamp(float x) { // out_kernel only
    float xc = __builtin_amdgcn_fmed3f(x, -9.0f, 9.0f);
    float u  = fexp2(xc * TANH2C);
    return fmaf(-2.0f, frcp(u + 1.0f), 1.0f);
}
__device__ __forceinline__ float fast_tanh_nc(float x) {
    float u = fexp2(x * TANH2C);
    return fmaf(-2.0f, frcp(u + 1.0f), 1.0f);
}

// ---- DPP / lane helpers ----------------------------------------------------
template <int CTRL>
__device__ __forceinline__ float dpp_add(float v) {
    int t = __builtin_amdgcn_update_dpp(0, __float_as_int(v), CTRL, 0xF, 0xF, true);
    return v + __int_as_float(t);
}
__device__ __forceinline__ float allsum16(float x) {
    x = dpp_add<0xB1>(x);   // quad_perm xor1
    x = dpp_add<0x4E>(x);   // quad_perm xor2
    x = dpp_add<0x141>(x);  // row_half_mirror
    x = dpp_add<0x140>(x);  // row_mirror
    return x;
}
__device__ __forceinline__ int dpp_xor1_i(int v) {
    return __builtin_amdgcn_update_dpp(0, v, 0xB1, 0xF, 0xF, true);
}
__device__ __forceinline__ float rl(float x, int lane) {
    return __int_as_float(__builtin_amdgcn_readlane(__float_as_int(x), lane));
}
__device__ __forceinline__ float bpf(int addr, float x) {
    return __int_as_float(__builtin_amdgcn_ds_bpermute(addr, __float_as_int(x)));
}

// ---------------------------------------------------------------------------
// init: all window ICs = global Y0 guess (f32)
// ---------------------------------------------------------------------------
__global__ void init_kernel(const float* __restrict__ inputs, float2* icg) {
    int w = blockIdx.x * blockDim.x + threadIdx.x;
    if (w < WIN) icg[w] = make_float2(inputs[0], inputs[1]);
}

// ---------------------------------------------------------------------------
// Newton-Parareal sweep, FOUR trajectory slots per wave (3 used):
//   quad 0 = unperturbed, quad 1 = +FD_EPS0 on s0, quads 2,3 = +FD_EPS1 on s1.
// Structure validated R6-R9 (absmax at bf16 floor; 309 us @ 3 waves/SIMD).
// Non-uniform windows: LEN = 86 for wnd<1024 else 85.
// UNCHANGED from R9.
// ---------------------------------------------------------------------------
__global__ __launch_bounds__(64, 1) void sweep_kernel(
    const float* __restrict__ inputs,   // (T,5)
    const float* __restrict__ lday,     // (T,)
    const float* __restrict__ W1, const float* __restrict__ b1,
    const float* __restrict__ W2, const float* __restrict__ b2,
    const float* __restrict__ W3, const float* __restrict__ b3,
    float* __restrict__ traj,           // (T,2)
    const float2* __restrict__ icg,     // window ICs (read, f32)
    double2* __restrict__ E)            // end states (write), 3*WIN
{
    const int lane = threadIdx.x;
    const int col  = lane & 15;
    const int quad = lane >> 4;
    const int j32  = lane & 31;
    const int half = lane >> 5;
    const bool odd = (lane & 1) != 0;

    const int wnd  = blockIdx.x;
    const int S    = wnd * 85 + ((wnd < 1024) ? wnd : 1024);
    const int LEN  = (wnd < 1024) ? 86 : 85;
    const int endStep = (S + LEN < T_TOTAL - 1) ? (S + LEN) : (T_TOTAL - 1);

    // layer-1 weights, pre-scaled by 2log2e
    float w1c0 = W1[0 * HID + j32] * TANH2C, w1c1 = W1[1 * HID + j32] * TANH2C;
    float w1c2 = W1[2 * HID + j32] * TANH2C, w1c3 = W1[3 * HID + j32] * TANH2C;
    float b1j = b1[j32] * TANH2C;
    PIN(w1c0); PIN(w1c1); PIN(w1c2); PIN(w1c3); PIN(b1j);

    // W2*2log2e as f16 hi/lo B-fragments
    f16x8 Bhi0, Blo0, Bhi1, Blo1;
#pragma unroll
    for (int jj = 0; jj < 8; ++jj) {
        float w0 = W2[(quad * 8 + jj) * HID + col] * TANH2C;
        float w1v = W2[(quad * 8 + jj) * HID + col + 16] * TANH2C;
        _Float16 h0 = (_Float16)w0, h1v = (_Float16)w1v;
        Bhi0[jj] = h0;  Blo0[jj] = (_Float16)(w0 - (float)h0);
        Bhi1[jj] = h1v; Blo1[jj] = (_Float16)(w1v - (float)h1v);
    }
    PIN(Bhi0); PIN(Blo0); PIN(Bhi1); PIN(Blo1);

    float b2a2 = b2[col] * TANH2C, b2b2 = b2[col + 16] * TANH2C;
    f32x4 cb0 = {b2a2, b2a2, b2a2, b2a2};
    f32x4 cb1 = {b2b2, b2b2, b2b2, b2b2};
    PIN(cb0); PIN(cb1);

    // layer-3 weights: 5 channels per 16-lane quad
    float wca[5], wcb[5];
#pragma unroll
    for (int c = 0; c < 5; ++c) {
        wca[c] = W3[col * 5 + c] * LOG2E;
        wcb[c] = W3[(col + 16) * 5 + c] * LOG2E;
        PIN(wca[c]); PIN(wcb[c]);
    }

    float m0 = (col == 0) ? 1.f : 0.f;
    float m1 = (col == 1) ? 1.f : 0.f;
    float m2 = (col == 2) ? 1.f : 0.f;
    float m3 = (col == 3) ? 1.f : 0.f;
    float m4 = (col == 4) ? 1.f : 0.f;
    float m5 = (col == 5) ? 1.f : 0.f;
    float m6 = (col == 6) ? 1.f : 0.f;
    float m7 = (col == 7) ? 1.f : 0.f;
    float m8 = (col == 8) ? 1.f : 0.f;
    float sig1m = (col >= 5 && col <= 8) ? 1.f : 0.f;
    float zb = b3[(col < 5) ? col : 0];
    float zconst = (col < 5) ? zb * LOG2E : 0.f;
    PIN(m0); PIN(m1); PIN(m2); PIN(m3); PIN(m4); PIN(m5); PIN(m6); PIN(m7); PIN(m8);
    PIN(sig1m); PIN(zconst);

    int psel = (lane & 1) ? 0x01000504 : 0x05040100;
    // A-build gather base by row class r&3: {A,B,C,C-dup} -> {+0,+128,+4,+132}
    int l3 = lane & 3;
    int roff = (l3 == 1) ? 128 : (l3 == 2) ? 4 : (l3 == 3) ? 132 : 0;
    int bbase = 32 * quad + roff;
    int bp0 = bbase, bp1 = bbase + 8, bp2 = bbase + 16, bp3 = bbase + 24;
    PIN(psel); PIN(bp0); PIN(bp1); PIN(bp2); PIN(bp3);

    // per-quad output-gather addresses (bytes)
    int qb = 64 * quad;
    int a_sh0 = qb + 0,  a_sh1 = qb + 4,  a_sh2 = qb + 8;
    int a_e3  = qb + 12, a_e4  = qb + 16, a_sg0 = qb + 20, a_sg1 = qb + 24;
    PIN(a_sh0); PIN(a_sh1); PIN(a_sh2); PIN(a_e3); PIN(a_e4); PIN(a_sg0); PIN(a_sg1);

    float2 ic = icg[wnd];
    double y0 = (double)ic.x + ((quad == 1) ? FD_EPS0 : 0.0);
    double y1 = (double)ic.y + ((quad >= 2) ? FD_EPS1 : 0.0);
    float2* traj2 = (float2*)traj;
    if (lane == 0 && wnd == 0)
        traj2[0] = make_float2(ic.x, ic.y);

    auto rhs = [&](float s0q, float s1q, float base, float stm, float ld, float zoffk,
                   float& d0, float& d1, float& rout) {
        // broadcast the three trajectory states for layer-1
        float s0A = rl(s0q, 0),  s1A = rl(s1q, 0);
        float s0B = rl(s0q, 16), s1B = rl(s1q, 16);
        float s0C = rl(s0q, 32), s1C = rl(s1q, 32);
        float s0p = half ? s0B : s0A;
        float s1p = half ? s1B : s1A;
        // layer-1: primary (A/B by half) and C (all lanes)
        float prep = fmaf(s1p, w1c1, fmaf(s0p, w1c0, base));
        float prec = fmaf(s1C, w1c1, fmaf(s0C, w1c0, base));
        float up_ = fexp2(prep);
        float uc_ = fexp2(prec);
        float h1p = fmaf(-2.0f, frcp(up_ + 1.0f), 1.0f);
        float h1c = fmaf(-2.0f, frcp(uc_ + 1.0f), 1.0f);
        union { _Float16 h; unsigned short u; } cvp, cvc;
        cvp.h = (_Float16)h1p; cvc.h = (_Float16)h1c;
        int ownp = (int)cvp.u, ownc = (int)cvc.u;
        int nbp = dpp_xor1_i(ownp), nbc = dpp_xor1_i(ownc);
        int pkp = __builtin_amdgcn_perm(nbp, ownp, psel);
        int pkc = __builtin_amdgcn_perm(nbc, ownc, psel);
        int pk  = odd ? pkc : pkp;
        int g0i = __builtin_amdgcn_ds_bpermute(bp0, pk);
        int g1i = __builtin_amdgcn_ds_bpermute(bp1, pk);
        int g2i = __builtin_amdgcn_ds_bpermute(bp2, pk);
        int g3i = __builtin_amdgcn_ds_bpermute(bp3, pk);
        union { int i[4]; f16x8 h; } au;
        au.i[0] = g0i; au.i[1] = g1i; au.i[2] = g2i; au.i[3] = g3i;
        f16x8 A = au.h;
        f32x4 zz = {0.f, 0.f, 0.f, 0.f};
        f32x4 chi0 = __builtin_amdgcn_mfma_f32_16x16x32_f16(A, Bhi0, cb0, 0, 0, 0);
        f32x4 clo0 = __builtin_amdgcn_mfma_f32_16x16x32_f16(A, Blo0, zz, 0, 0, 0);
        f32x4 chi1 = __builtin_amdgcn_mfma_f32_16x16x32_f16(A, Bhi1, cb1, 0, 0, 0);
        f32x4 clo1 = __builtin_amdgcn_mfma_f32_16x16x32_f16(A, Blo1, zz, 0, 0, 0);
        // per-quad trajectory row select (C rows: 4q+0=A, +1=B, +2=C, +3=C-dup)
        float tA0 = chi0[0] + clo0[0], tB0 = chi0[1] + clo0[1], tC0 = chi0[2] + clo0[2];
        float tA1 = chi1[0] + clo1[0], tB1 = chi1[1] + clo1[1], tC1 = chi1[2] + clo1[2];
        float t0 = (quad == 1) ? tB0 : (quad >= 2) ? tC0 : tA0;
        float t1 = (quad == 1) ? tB1 : (quad >= 2) ? tC1 : tA1;
        float ua = fexp2(t0);
        float ub = fexp2(t1);
        float g0 = fmaf(-2.0f, frcp(ua + 1.0f), 1.0f);
        float g1 = fmaf(-2.0f, frcp(ub + 1.0f), 1.0f);
        float r0 = fmaf(g0, wca[0], g1 * wcb[0]);
        float r1 = fmaf(g0, wca[1], g1 * wcb[1]);
        float r2 = fmaf(g0, wca[2], g1 * wcb[2]);
        float r3 = fmaf(g0, wca[3], g1 * wcb[3]);
        float r4 = fmaf(g0, wca[4], g1 * wcb[4]);
        float s0r = allsum16(r0);
        float s1r = allsum16(r1);
        float s2r = allsum16(r2);
        float s3r = allsum16(r3);
        float s4r = allsum16(r4);
        float zs0 = s0q * NEG10LOG2E;           // own quad's trajectory
        float zs1 = s1q * NEG10LOG2E;
        float zoff = fmaf(zs0, m5, fmaf(zs1, m6, zoffk));
        float zarg = fmaf(s0r, m0, fmaf(s1r, m1, fmaf(s2r, m2,
                     fmaf(s3r, m3, fmaf(s4r, m4, zoff)))));
        float u = fexp2(zarg);
        float r = frcp(u + sig1m);
        float w = fmaf(0.5f, u, -0.5f * r);
        float sh0 = bpf(a_sh0, w), sh1 = bpf(a_sh1, w), sh2 = bpf(a_sh2, w);
        float e3  = bpf(a_e3, u),  e4  = bpf(a_e4, u);
        float sg0 = bpf(a_sg0, r), sg1 = bpf(a_sg1, r);
        float p_snow = fmaxf(sh0 * stm, 0.f);
        float p_rain = fmaxf(sh1, 0.f);
        float melt   = fmaxf(sg0 * sh2, 0.f);
        float etq    = sg1 * fmaf(e3, ld, e4);
        d0 = p_snow - melt;
        d1 = (p_rain + melt) - etq;
        rout = r;
    };

    float pA = inputs[S * 5 + 2],       tmA = inputs[S * 5 + 3],       ldA = lday[S];
    float pB = inputs[(S + 1) * 5 + 2], tmB = inputs[(S + 1) * 5 + 3], ldB = lday[S + 1];
    float pC = inputs[(S + 2) * 5 + 2], tmC = inputs[(S + 2) * 5 + 3], ldC = lday[S + 2];
    float stmA = fast_sig10(-tmA);
    float stmB = fast_sig10(-tmB);
    float stmm = fast_sig10(-0.5f * (tmA + tmB));
    float baseA = fmaf(pA, w1c2, fmaf(tmA, w1c3, b1j));
    float baseB = fmaf(pB, w1c2, fmaf(tmB, w1c3, b1j));

    for (int n = S; n < endStep; ++n) {
        const float ldm = 0.5f * (ldA + ldB);
        const float pm  = 0.5f * (pA + pB);
        const float tmm = 0.5f * (tmA + tmB);
        const float basem = fmaf(pm, w1c2, fmaf(tmm, w1c3, b1j));
        const float ztm_m = (0.5f * (tmB + tmC)) * POS10LOG2E;
        const float ztm_b = tmC * POS10LOG2E;
        const float zoffk = fmaf(ztm_m, m7, fmaf(ztm_b, m8, zconst));

        const float fy0 = (float)y0, fy1 = (float)y1;
        float k10, k11, k20, k21, k30, k31, k40, k41, rd;
        rhs(fy0,                  fy1,                  baseA, stmA, ldA, zoffk, k10, k11, rd);
        rhs(fmaf(0.5f, k10, fy0), fmaf(0.5f, k11, fy1), basem, stmm, ldm, zoffk, k20, k21, rd);
        rhs(fmaf(0.5f, k20, fy0), fmaf(0.5f, k21, fy1), basem, stmm, ldm, zoffk, k30, k31, rd);
        rhs(fy0 + k30,            fy1 + k31,            baseB, stmB, ldB, zoffk, k40, k41, rd);
        const float stmm_n = rl(rd, 7);
        const float stmB_n = rl(rd, 8);

        const float s0sum = (k10 + 2.0f * k20) + (2.0f * k30 + k40);
        const float s1sum = (k11 + 2.0f * k21) + (2.0f * k31 + k41);
        y0 += (1.0 / 6.0) * (double)s0sum;
        y1 += (1.0 / 6.0) * (double)s1sum;

        if (lane == 0)
            traj2[n + 1] = make_float2((float)y0, (float)y1);

        stmA = stmB; stmB = stmB_n; stmm = stmm_n;
        baseA = baseB;
        baseB = fmaf(pC, w1c2, fmaf(tmC, w1c3, b1j));
        pA = pB; tmA = tmB; ldA = ldB;
        pB = pC; tmB = tmC; ldB = ldC;
        const int np3 = (n + 3 < T_TOTAL) ? (n + 3) : (T_TOTAL - 1);
        pC = inputs[np3 * 5 + 2]; tmC = inputs[np3 * 5 + 3]; ldC = lday[np3];
    }

    if (lane == 0)  E[wnd]           = make_double2(y0, y1);  // unperturbed
    if (lane == 16) E[WIN + wnd]     = make_double2(y0, y1);  // +eps0 on s0
    if (lane == 32) E[2 * WIN + wnd] = make_double2(y0, y1);  // +eps1 on s1
}

// ---------------------------------------------------------------------------
// Sequential Newton-Parareal correction — chunked double-buffered LDS.
// R9 post-mortem: the global-icg register pipeline was slow because vmcnt is
// a single in-order queue — waiting on prefetch LOADS drains the preceding
// icg STORES too (~60 cyc/window). Fix: serial loop touches ONLY LDS (reads)
// + fire-and-forget global stores (vmcnt never waited), as in fast R8.
// 3 chunks of 1024 windows; lanes 1-63 stage chunk c+1 (global->LDS, with J
// differenced in f64 then clamped to f32 — identical math to R8/R9) while
// lane 0 serially processes chunk c (~28 cyc/window). 2x7x1024x4 = 57 KB LDS.
// Lane-0 stores (chunk c) and stager reads (chunk c+1) touch disjoint icg
// ranges — no race. Clamps wide-open (R6-validated). J01 := 0.
// ---------------------------------------------------------------------------
__global__ __launch_bounds__(64) void correct_kernel(
    const float* __restrict__ inputs,
    const double2* __restrict__ E,
    float2* __restrict__ icg) {
    __shared__ float sJ00[2][CH], sJ10[2][CH], sJ11[2][CH];
    __shared__ float sE0x[2][CH], sE0y[2][CH];
    __shared__ float sGx[2][CH],  sGy[2][CH];     // 2*7*1024*4 = 57344 B
    const int tid = threadIdx.x;

    auto stage_one = [&](int buf, int i, int w) {
        double2 e0 = E[w];
        double2 e1 = E[WIN + w];
        double2 e2 = E[2 * WIN + w];
        float2 g   = icg[w];
        float J00 = (float)((e1.x - e0.x) * (1.0 / FD_EPS0));
        float J10 = (float)((e1.y - e0.y) * (1.0 / FD_EPS0));
        float J11 = (float)((e2.y - e0.y) * (1.0 / FD_EPS1));
        sJ00[buf][i] = fminf(fmaxf(J00, -0.15f), 1.15f);   // wide-open (R6)
        sJ10[buf][i] = fminf(fmaxf(J10, -0.30f), 1.80f);
        sJ11[buf][i] = fminf(fmaxf(J11,  0.00f), 1.10f);
        sE0x[buf][i] = (float)e0.x; sE0y[buf][i] = (float)e0.y;
        sGx[buf][i]  = g.x;         sGy[buf][i]  = g.y;
    };

    // prologue: all 64 lanes stage chunk 0 into buffer 0
    for (int i = tid; i < CH; i += 64) stage_one(0, i, i);
    __syncthreads();

    float y0c = inputs[0];
    float y1c = inputs[1];
    for (int c = 0; c < 3; ++c) {
        const int buf = c & 1;
        if (tid == 0) {
            // serial recurrence over chunk c: LDS reads + un-waited stores only
            const int wbase = c * CH;
            for (int i = 0; i < CH; ++i) {
                float d0 = y0c - sGx[buf][i];
                float d1 = y1c - sGy[buf][i];
                d0 = fminf(fmaxf(d0, -50.0f), 50.0f);      // trust region
                d1 = fminf(fmaxf(d1, -400.0f), 400.0f);
                icg[wbase + i] = make_float2(y0c, y1c);    // fire-and-forget
                y0c = fmaf(sJ00[buf][i], d0, sE0x[buf][i]);        // J01 = 0
                y1c = fmaf(sJ10[buf][i], d0, fmaf(sJ11[buf][i], d1, sE0y[buf][i]));
                y0c = fminf(fmaxf(y0c, -5.0f), 1000.0f);   // physical sanity
                y1c = fminf(fmaxf(y1c, -5.0f), 5000.0f);
            }
        } else if (c + 1 < 3) {
            // lanes 1-63 stage chunk c+1 into the other buffer, overlapped
            for (int i = tid - 1; i < CH; i += 63)
                stage_one((c + 1) & 1, i, (c + 1) * CH + i);
        }
        __syncthreads();
    }
}

// ---------------------------------------------------------------------------
// Parallel readout: out[t] = mlp(relu(state), p, tm)[4]
// ---------------------------------------------------------------------------
__global__ __launch_bounds__(256) void out_kernel(
    const float* __restrict__ inputs,
    const float* __restrict__ traj,
    const float* __restrict__ W1, const float* __restrict__ b1,
    const float* __restrict__ W2, const float* __restrict__ b2,
    const float* __restrict__ W3, const float* __restrict__ b3,
    float* __restrict__ out)
{
    __shared__ float sW1[4 * HID];
    __shared__ float sb1[HID];
    __shared__ float sW2T[HID * HID];
    __shared__ float sb2[HID];
    __shared__ float sw3[HID];
    for (int i = threadIdx.x; i < 4 * HID; i += 256) sW1[i] = W1[i];
    for (int i = threadIdx.x; i < HID; i += 256) {
        sb1[i] = b1[i]; sb2[i] = b2[i]; sw3[i] = W3[i * 5 + 4];
    }
    for (int idx = threadIdx.x; idx < HID * HID; idx += 256) {
        int jj = idx >> 5, ii = idx & 31;
        sW2T[idx] = W2[ii * HID + jj];
    }
    __syncthreads();

    int t = blockIdx.x * 256 + threadIdx.x;
    if (t >= T_TOTAL) return;

    float2 st = ((const float2*)traj)[t];
    float s0 = fmaxf(st.x, 0.0f);
    float s1 = fmaxf(st.y, 0.0f);
    float p  = inputs[t * 5 + 2];
    float tm = inputs[t * 5 + 3];

    float h1[HID];
#pragma unroll
    for (int jj = 0; jj < HID; ++jj) {
        float pre = fmaf(s0, sW1[jj], fmaf(s1, sW1[HID + jj],
                    fmaf(p, sW1[2 * HID + jj],
                    fmaf(tm, sW1[3 * HID + jj], sb1[jj]))));
        h1[jj] = fast_tanh_clamp(pre);
    }
    float o = b3[4];
#pragma unroll 4
    for (int jj = 0; jj < HID; ++jj) {
        float a0 = sb2[jj], a1 = 0.f, a2 = 0.f, a3 = 0.f;
#pragma unroll
        for (int ii = 0; ii < HID; ii += 4) {
            a0 = fmaf(h1[ii + 0], sW2T[jj * HID + ii + 0], a0);
            a1 = fmaf(h1[ii + 1], sW2T[jj * HID + ii + 1], a1);
            a2 = fmaf(h1[ii + 2], sW2T[jj * HID + ii + 2], a2);
            a3 = fmaf(h1[ii + 3], sW2T[jj * HID + ii + 3], a3);
        }
        o = fmaf(fast_tanh_nc((a0 + a1) + (a2 + a3)), sw3[jj], o);
    }
    out[t] = o;
}

extern "C" void kernel_launch(void* const* d_in, const int* in_sizes, int n_in,
                              void* d_out, int out_size, void* d_ws, size_t ws_size,
                              hipStream_t stream) {
    (void)in_sizes; (void)n_in; (void)out_size; (void)ws_size;
    const float* inputs = (const float*)d_in[0];
    const float* lday   = (const float*)d_in[1];
    const float* W1     = (const float*)d_in[2];
    const float* b1     = (const float*)d_in[3];
    const float* W2     = (const float*)d_in[4];
    const float* b2     = (const float*)d_in[5];
    const float* W3     = (const float*)d_in[6];
    const float* b3     = (const float*)d_in[7];
    float* out  = (float*)d_out;
    float* traj = (float*)d_ws;                 // T*2 floats = 2 MB

    // small Parareal arrays live in d_out (scratch until out_kernel, 1 MB)
    // E = 3*WIN double2 = 147456 B at offset 0; icg = WIN float2 = 24576 B
    // at offset 196608. Total 221184 <= 1 MB.
    char* scr = (char*)d_out;
    double2* E  = (double2*)scr;
    float2* icg = (float2*)(scr + 196608);

    hipLaunchKernelGGL(init_kernel, dim3((WIN + 255) / 256), dim3(256), 0, stream,
                       inputs, icg);
    for (int k = 0; k < NSWEEP - 1; ++k) {
        hipLaunchKernelGGL(sweep_kernel, dim3(WIN), dim3(64), 0, stream,
                           inputs, lday, W1, b1, W2, b2, W3, b3, traj, icg, E);
        hipLaunchKernelGGL(correct_kernel, dim3(1), dim3(64), 0, stream,
                           inputs, E, icg);
    }
    // final sweep: trajectory becomes self-consistent with corrected ICs
    hipLaunchKernelGGL(sweep_kernel, dim3(WIN), dim3(64), 0, stream,
                       inputs, lday, W1, b1, W2, b2, W3, b3, traj, icg, E);
    hipLaunchKernelGGL(out_kernel, dim3((T_TOTAL + 255) / 256), dim3(256), 0, stream,
                       inputs, traj, W1, b1, W2, b2, W3, b3, out);
}

// Round 12
// 2443.992 us; speedup vs baseline: 1.0335x; 1.0335x over previous
//
#include <hip/hip_runtime.h>
#include <math.h>

#define T_TOTAL 262144
#define HID 32
#define WIN 3072                      /* windows: 85-86 serial steps each */
/* window geometry: first 1024 windows have 86 steps, rest 85.
   S(w) = 85*w + min(w,1024); contiguous, covers [0, 262144). */
#define NSWEEP 6                      /* total sweeps; NSWEEP-1 corrections */
#define CH 1024                       /* correction chunk size (3 chunks) */
#define FD_EPS0 4.0                   /* FD perturbation on s0 (snow) */
#define FD_EPS1 8.0                   /* FD perturbation on s1 (water) */
#define LOG2E 1.4426950408889634f
#define TANH2C 2.8853900817779268f    /* 2*log2e */
#define NEG10LOG2E (-14.426950408889634f)
#define POS10LOG2E (14.426950408889634f)

#define PIN(x) asm volatile("" : "+v"(x))

typedef _Float16 f16x8 __attribute__((ext_vector_type(8)));
typedef float f32x4 __attribute__((ext_vector_type(4)));

__device__ __forceinline__ float fexp2(float x) { return __builtin_amdgcn_exp2f(x); }
__device__ __forceinline__ float frcp(float x)  { return __builtin_amdgcn_rcpf(x); }
__device__ __forceinline__ float fast_sig10(float x) {
    return frcp(1.0f + fexp2(x * NEG10LOG2E));
}
__device__ __forceinline__ float fast_tanh_clamp(float x) { // out_kernel only
    float xc = __builtin_amdgcn_fmed3f(x, -9.0f, 9.0f);
    float u  = fexp2(xc * TANH2C);
    return fmaf(-2.0f, frcp(u + 1.0f), 1.0f);
}
__device__ __forceinline__ float fast_tanh_nc(float x) {
    float u = fexp2(x * TANH2C);
    return fmaf(-2.0f, frcp(u + 1.0f), 1.0f);
}

// ---- DPP / lane helpers ----------------------------------------------------
template <int CTRL>
__device__ __forceinline__ float dpp_add(float v) {
    int t = __builtin_amdgcn_update_dpp(0, __float_as_int(v), CTRL, 0xF, 0xF, true);
    return v + __int_as_float(t);
}
__device__ __forceinline__ float allsum16(float x) {
    x = dpp_add<0xB1>(x);   // quad_perm xor1
    x = dpp_add<0x4E>(x);   // quad_perm xor2
    x = dpp_add<0x141>(x);  // row_half_mirror
    x = dpp_add<0x140>(x);  // row_mirror
    return x;
}
__device__ __forceinline__ int dpp_xor1_i(int v) {
    return __builtin_amdgcn_update_dpp(0, v, 0xB1, 0xF, 0xF, true);
}
__device__ __forceinline__ float rl(float x, int lane) {
    return __int_as_float(__builtin_amdgcn_readlane(__float_as_int(x), lane));
}
__device__ __forceinline__ float bpf(int addr, float x) {
    return __int_as_float(__builtin_amdgcn_ds_bpermute(addr, __float_as_int(x)));
}

// ---------------------------------------------------------------------------
// init: all window ICs = global Y0 guess (f32)
// ---------------------------------------------------------------------------
__global__ void init_kernel(const float* __restrict__ inputs, float2* icg) {
    int w = blockIdx.x * blockDim.x + threadIdx.x;
    if (w < WIN) icg[w] = make_float2(inputs[0], inputs[1]);
}

// ---------------------------------------------------------------------------
// Newton-Parareal sweep, FOUR trajectory slots per wave (3 used):
//   quad 0 = unperturbed, quad 1 = +FD_EPS0 on s0, quads 2,3 = +FD_EPS1 on s1.
// Structure validated R6-R11 (absmax at bf16 floor; ~307 us @ 3 waves/SIMD).
// Non-uniform windows: LEN = 86 for wnd<1024 else 85.
// UNCHANGED from R9.
// ---------------------------------------------------------------------------
__global__ __launch_bounds__(64, 1) void sweep_kernel(
    const float* __restrict__ inputs,   // (T,5)
    const float* __restrict__ lday,     // (T,)
    const float* __restrict__ W1, const float* __restrict__ b1,
    const float* __restrict__ W2, const float* __restrict__ b2,
    const float* __restrict__ W3, const float* __restrict__ b3,
    float* __restrict__ traj,           // (T,2)
    const float2* __restrict__ icg,     // window ICs (read, f32)
    double2* __restrict__ E)            // end states (write), 3*WIN
{
    const int lane = threadIdx.x;
    const int col  = lane & 15;
    const int quad = lane >> 4;
    const int j32  = lane & 31;
    const int half = lane >> 5;
    const bool odd = (lane & 1) != 0;

    const int wnd  = blockIdx.x;
    const int S    = wnd * 85 + ((wnd < 1024) ? wnd : 1024);
    const int LEN  = (wnd < 1024) ? 86 : 85;
    const int endStep = (S + LEN < T_TOTAL - 1) ? (S + LEN) : (T_TOTAL - 1);

    // layer-1 weights, pre-scaled by 2log2e
    float w1c0 = W1[0 * HID + j32] * TANH2C, w1c1 = W1[1 * HID + j32] * TANH2C;
    float w1c2 = W1[2 * HID + j32] * TANH2C, w1c3 = W1[3 * HID + j32] * TANH2C;
    float b1j = b1[j32] * TANH2C;
    PIN(w1c0); PIN(w1c1); PIN(w1c2); PIN(w1c3); PIN(b1j);

    // W2*2log2e as f16 hi/lo B-fragments
    f16x8 Bhi0, Blo0, Bhi1, Blo1;
#pragma unroll
    for (int jj = 0; jj < 8; ++jj) {
        float w0 = W2[(quad * 8 + jj) * HID + col] * TANH2C;
        float w1v = W2[(quad * 8 + jj) * HID + col + 16] * TANH2C;
        _Float16 h0 = (_Float16)w0, h1v = (_Float16)w1v;
        Bhi0[jj] = h0;  Blo0[jj] = (_Float16)(w0 - (float)h0);
        Bhi1[jj] = h1v; Blo1[jj] = (_Float16)(w1v - (float)h1v);
    }
    PIN(Bhi0); PIN(Blo0); PIN(Bhi1); PIN(Blo1);

    float b2a2 = b2[col] * TANH2C, b2b2 = b2[col + 16] * TANH2C;
    f32x4 cb0 = {b2a2, b2a2, b2a2, b2a2};
    f32x4 cb1 = {b2b2, b2b2, b2b2, b2b2};
    PIN(cb0); PIN(cb1);

    // layer-3 weights: 5 channels per 16-lane quad
    float wca[5], wcb[5];
#pragma unroll
    for (int c = 0; c < 5; ++c) {
        wca[c] = W3[col * 5 + c] * LOG2E;
        wcb[c] = W3[(col + 16) * 5 + c] * LOG2E;
        PIN(wca[c]); PIN(wcb[c]);
    }

    float m0 = (col == 0) ? 1.f : 0.f;
    float m1 = (col == 1) ? 1.f : 0.f;
    float m2 = (col == 2) ? 1.f : 0.f;
    float m3 = (col == 3) ? 1.f : 0.f;
    float m4 = (col == 4) ? 1.f : 0.f;
    float m5 = (col == 5) ? 1.f : 0.f;
    float m6 = (col == 6) ? 1.f : 0.f;
    float m7 = (col == 7) ? 1.f : 0.f;
    float m8 = (col == 8) ? 1.f : 0.f;
    float sig1m = (col >= 5 && col <= 8) ? 1.f : 0.f;
    float zb = b3[(col < 5) ? col : 0];
    float zconst = (col < 5) ? zb * LOG2E : 0.f;
    PIN(m0); PIN(m1); PIN(m2); PIN(m3); PIN(m4); PIN(m5); PIN(m6); PIN(m7); PIN(m8);
    PIN(sig1m); PIN(zconst);

    int psel = (lane & 1) ? 0x01000504 : 0x05040100;
    // A-build gather base by row class r&3: {A,B,C,C-dup} -> {+0,+128,+4,+132}
    int l3 = lane & 3;
    int roff = (l3 == 1) ? 128 : (l3 == 2) ? 4 : (l3 == 3) ? 132 : 0;
    int bbase = 32 * quad + roff;
    int bp0 = bbase, bp1 = bbase + 8, bp2 = bbase + 16, bp3 = bbase + 24;
    PIN(psel); PIN(bp0); PIN(bp1); PIN(bp2); PIN(bp3);

    // per-quad output-gather addresses (bytes)
    int qb = 64 * quad;
    int a_sh0 = qb + 0,  a_sh1 = qb + 4,  a_sh2 = qb + 8;
    int a_e3  = qb + 12, a_e4  = qb + 16, a_sg0 = qb + 20, a_sg1 = qb + 24;
    PIN(a_sh0); PIN(a_sh1); PIN(a_sh2); PIN(a_e3); PIN(a_e4); PIN(a_sg0); PIN(a_sg1);

    float2 ic = icg[wnd];
    double y0 = (double)ic.x + ((quad == 1) ? FD_EPS0 : 0.0);
    double y1 = (double)ic.y + ((quad >= 2) ? FD_EPS1 : 0.0);
    float2* traj2 = (float2*)traj;
    if (lane == 0 && wnd == 0)
        traj2[0] = make_float2(ic.x, ic.y);

    auto rhs = [&](float s0q, float s1q, float base, float stm, float ld, float zoffk,
                   float& d0, float& d1, float& rout) {
        // broadcast the three trajectory states for layer-1
        float s0A = rl(s0q, 0),  s1A = rl(s1q, 0);
        float s0B = rl(s0q, 16), s1B = rl(s1q, 16);
        float s0C = rl(s0q, 32), s1C = rl(s1q, 32);
        float s0p = half ? s0B : s0A;
        float s1p = half ? s1B : s1A;
        // layer-1: primary (A/B by half) and C (all lanes)
        float prep = fmaf(s1p, w1c1, fmaf(s0p, w1c0, base));
        float prec = fmaf(s1C, w1c1, fmaf(s0C, w1c0, base));
        float up_ = fexp2(prep);
        float uc_ = fexp2(prec);
        float h1p = fmaf(-2.0f, frcp(up_ + 1.0f), 1.0f);
        float h1c = fmaf(-2.0f, frcp(uc_ + 1.0f), 1.0f);
        union { _Float16 h; unsigned short u; } cvp, cvc;
        cvp.h = (_Float16)h1p; cvc.h = (_Float16)h1c;
        int ownp = (int)cvp.u, ownc = (int)cvc.u;
        int nbp = dpp_xor1_i(ownp), nbc = dpp_xor1_i(ownc);
        int pkp = __builtin_amdgcn_perm(nbp, ownp, psel);
        int pkc = __builtin_amdgcn_perm(nbc, ownc, psel);
        int pk  = odd ? pkc : pkp;
        int g0i = __builtin_amdgcn_ds_bpermute(bp0, pk);
        int g1i = __builtin_amdgcn_ds_bpermute(bp1, pk);
        int g2i = __builtin_amdgcn_ds_bpermute(bp2, pk);
        int g3i = __builtin_amdgcn_ds_bpermute(bp3, pk);
        union { int i[4]; f16x8 h; } au;
        au.i[0] = g0i; au.i[1] = g1i; au.i[2] = g2i; au.i[3] = g3i;
        f16x8 A = au.h;
        f32x4 zz = {0.f, 0.f, 0.f, 0.f};
        f32x4 chi0 = __builtin_amdgcn_mfma_f32_16x16x32_f16(A, Bhi0, cb0, 0, 0, 0);
        f32x4 clo0 = __builtin_amdgcn_mfma_f32_16x16x32_f16(A, Blo0, zz, 0, 0, 0);
        f32x4 chi1 = __builtin_amdgcn_mfma_f32_16x16x32_f16(A, Bhi1, cb1, 0, 0, 0);
        f32x4 clo1 = __builtin_amdgcn_mfma_f32_16x16x32_f16(A, Blo1, zz, 0, 0, 0);
        // per-quad trajectory row select (C rows: 4q+0=A, +1=B, +2=C, +3=C-dup)
        float tA0 = chi0[0] + clo0[0], tB0 = chi0[1] + clo0[1], tC0 = chi0[2] + clo0[2];
        float tA1 = chi1[0] + clo1[0], tB1 = chi1[1] + clo1[1], tC1 = chi1[2] + clo1[2];
        float t0 = (quad == 1) ? tB0 : (quad >= 2) ? tC0 : tA0;
        float t1 = (quad == 1) ? tB1 : (quad >= 2) ? tC1 : tA1;
        float ua = fexp2(t0);
        float ub = fexp2(t1);
        float g0 = fmaf(-2.0f, frcp(ua + 1.0f), 1.0f);
        float g1 = fmaf(-2.0f, frcp(ub + 1.0f), 1.0f);
        float r0 = fmaf(g0, wca[0], g1 * wcb[0]);
        float r1 = fmaf(g0, wca[1], g1 * wcb[1]);
        float r2 = fmaf(g0, wca[2], g1 * wcb[2]);
        float r3 = fmaf(g0, wca[3], g1 * wcb[3]);
        float r4 = fmaf(g0, wca[4], g1 * wcb[4]);
        float s0r = allsum16(r0);
        float s1r = allsum16(r1);
        float s2r = allsum16(r2);
        float s3r = allsum16(r3);
        float s4r = allsum16(r4);
        float zs0 = s0q * NEG10LOG2E;           // own quad's trajectory
        float zs1 = s1q * NEG10LOG2E;
        float zoff = fmaf(zs0, m5, fmaf(zs1, m6, zoffk));
        float zarg = fmaf(s0r, m0, fmaf(s1r, m1, fmaf(s2r, m2,
                     fmaf(s3r, m3, fmaf(s4r, m4, zoff)))));
        float u = fexp2(zarg);
        float r = frcp(u + sig1m);
        float w = fmaf(0.5f, u, -0.5f * r);
        float sh0 = bpf(a_sh0, w), sh1 = bpf(a_sh1, w), sh2 = bpf(a_sh2, w);
        float e3  = bpf(a_e3, u),  e4  = bpf(a_e4, u);
        float sg0 = bpf(a_sg0, r), sg1 = bpf(a_sg1, r);
        float p_snow = fmaxf(sh0 * stm, 0.f);
        float p_rain = fmaxf(sh1, 0.f);
        float melt   = fmaxf(sg0 * sh2, 0.f);
        float etq    = sg1 * fmaf(e3, ld, e4);
        d0 = p_snow - melt;
        d1 = (p_rain + melt) - etq;
        rout = r;
    };

    float pA = inputs[S * 5 + 2],       tmA = inputs[S * 5 + 3],       ldA = lday[S];
    float pB = inputs[(S + 1) * 5 + 2], tmB = inputs[(S + 1) * 5 + 3], ldB = lday[S + 1];
    float pC = inputs[(S + 2) * 5 + 2], tmC = inputs[(S + 2) * 5 + 3], ldC = lday[S + 2];
    float stmA = fast_sig10(-tmA);
    float stmB = fast_sig10(-tmB);
    float stmm = fast_sig10(-0.5f * (tmA + tmB));
    float baseA = fmaf(pA, w1c2, fmaf(tmA, w1c3, b1j));
    float baseB = fmaf(pB, w1c2, fmaf(tmB, w1c3, b1j));

    for (int n = S; n < endStep; ++n) {
        const float ldm = 0.5f * (ldA + ldB);
        const float pm  = 0.5f * (pA + pB);
        const float tmm = 0.5f * (tmA + tmB);
        const float basem = fmaf(pm, w1c2, fmaf(tmm, w1c3, b1j));
        const float ztm_m = (0.5f * (tmB + tmC)) * POS10LOG2E;
        const float ztm_b = tmC * POS10LOG2E;
        const float zoffk = fmaf(ztm_m, m7, fmaf(ztm_b, m8, zconst));

        const float fy0 = (float)y0, fy1 = (float)y1;
        float k10, k11, k20, k21, k30, k31, k40, k41, rd;
        rhs(fy0,                  fy1,                  baseA, stmA, ldA, zoffk, k10, k11, rd);
        rhs(fmaf(0.5f, k10, fy0), fmaf(0.5f, k11, fy1), basem, stmm, ldm, zoffk, k20, k21, rd);
        rhs(fmaf(0.5f, k20, fy0), fmaf(0.5f, k21, fy1), basem, stmm, ldm, zoffk, k30, k31, rd);
        rhs(fy0 + k30,            fy1 + k31,            baseB, stmB, ldB, zoffk, k40, k41, rd);
        const float stmm_n = rl(rd, 7);
        const float stmB_n = rl(rd, 8);

        const float s0sum = (k10 + 2.0f * k20) + (2.0f * k30 + k40);
        const float s1sum = (k11 + 2.0f * k21) + (2.0f * k31 + k41);
        y0 += (1.0 / 6.0) * (double)s0sum;
        y1 += (1.0 / 6.0) * (double)s1sum;

        if (lane == 0)
            traj2[n + 1] = make_float2((float)y0, (float)y1);

        stmA = stmB; stmB = stmB_n; stmm = stmm_n;
        baseA = baseB;
        baseB = fmaf(pC, w1c2, fmaf(tmC, w1c3, b1j));
        pA = pB; tmA = tmB; ldA = ldB;
        pB = pC; tmB = tmC; ldB = ldC;
        const int np3 = (n + 3 < T_TOTAL) ? (n + 3) : (T_TOTAL - 1);
        pC = inputs[np3 * 5 + 2]; tmC = inputs[np3 * 5 + 3]; ldC = lday[np3];
    }

    if (lane == 0)  E[wnd]           = make_double2(y0, y1);  // unperturbed
    if (lane == 16) E[WIN + wnd]     = make_double2(y0, y1);  // +eps0 on s0
    if (lane == 32) E[2 * WIN + wnd] = make_double2(y0, y1);  // +eps1 on s1
}

// ---------------------------------------------------------------------------
// Sequential Newton-Parareal correction — chunked double-buffered LDS,
// TWO WAVES (128 threads). R11 post-mortem: with a 64-thread block the
// serial lane-0 loop and the staging loop were two sides of a DIVERGENT
// branch in ONE wave64 -> hardware ran them sequentially under exec-mask
// (correction 125 us, worse than unpipelined). Producer/consumer overlap
// requires separate WAVES: wave 0 (lane 0) runs the serial recurrence over
// chunk c from LDS buffer c&1; wave 1 (tid>=64) stages chunk c+1 into the
// other buffer. Waves co-schedule (m114) and meet at __syncthreads.
// Math byte-identical to R8/R11 (f64 FD differences, f32 clamped J, f32
// recurrence). Serial chunk ~12 us; staging ~4 us hidden. ~45-55 us total.
// Clamps wide-open (R6-validated). J01 := 0.
// ---------------------------------------------------------------------------
__global__ __launch_bounds__(128) void correct_kernel(
    const float* __restrict__ inputs,
    const double2* __restrict__ E,
    float2* __restrict__ icg) {
    __shared__ float sJ00[2][CH], sJ10[2][CH], sJ11[2][CH];
    __shared__ float sE0x[2][CH], sE0y[2][CH];
    __shared__ float sGx[2][CH],  sGy[2][CH];     // 2*7*1024*4 = 57344 B
    const int tid = threadIdx.x;

    auto stage_one = [&](int buf, int i, int w) {
        double2 e0 = E[w];
        double2 e1 = E[WIN + w];
        double2 e2 = E[2 * WIN + w];
        float2 g   = icg[w];
        float J00 = (float)((e1.x - e0.x) * (1.0 / FD_EPS0));
        float J10 = (float)((e1.y - e0.y) * (1.0 / FD_EPS0));
        float J11 = (float)((e2.y - e0.y) * (1.0 / FD_EPS1));
        sJ00[buf][i] = fminf(fmaxf(J00, -0.15f), 1.15f);   // wide-open (R6)
        sJ10[buf][i] = fminf(fmaxf(J10, -0.30f), 1.80f);
        sJ11[buf][i] = fminf(fmaxf(J11,  0.00f), 1.10f);
        sE0x[buf][i] = (float)e0.x; sE0y[buf][i] = (float)e0.y;
        sGx[buf][i]  = g.x;         sGy[buf][i]  = g.y;
    };

    // prologue: all 128 threads stage chunk 0 into buffer 0
    for (int i = tid; i < CH; i += 128) stage_one(0, i, i);
    __syncthreads();

    float y0c = inputs[0];
    float y1c = inputs[1];
    for (int c = 0; c < 3; ++c) {
        const int buf = c & 1;
        if (tid == 0) {
            // wave 0: serial recurrence over chunk c — LDS reads +
            // fire-and-forget global stores only (vmcnt never waited)
            const int wbase = c * CH;
            for (int i = 0; i < CH; ++i) {
                float d0 = y0c - sGx[buf][i];
                float d1 = y1c - sGy[buf][i];
                d0 = fminf(fmaxf(d0, -50.0f), 50.0f);      // trust region
                d1 = fminf(fmaxf(d1, -400.0f), 400.0f);
                icg[wbase + i] = make_float2(y0c, y1c);    // fire-and-forget
                y0c = fmaf(sJ00[buf][i], d0, sE0x[buf][i]);        // J01 = 0
                y1c = fmaf(sJ10[buf][i], d0, fmaf(sJ11[buf][i], d1, sE0y[buf][i]));
                y0c = fminf(fmaxf(y0c, -5.0f), 1000.0f);   // physical sanity
                y1c = fminf(fmaxf(y1c, -5.0f), 5000.0f);
            }
        } else if (tid >= 64 && c + 1 < 3) {
            // wave 1: stage chunk c+1 into the other buffer, truly overlapped
            for (int i = tid - 64; i < CH; i += 64)
                stage_one((c + 1) & 1, i, (c + 1) * CH + i);
        }
        __syncthreads();
    }
}

// ---------------------------------------------------------------------------
// Parallel readout: out[t] = mlp(relu(state), p, tm)[4]
// ---------------------------------------------------------------------------
__global__ __launch_bounds__(256) void out_kernel(
    const float* __restrict__ inputs,
    const float* __restrict__ traj,
    const float* __restrict__ W1, const float* __restrict__ b1,
    const float* __restrict__ W2, const float* __restrict__ b2,
    const float* __restrict__ W3, const float* __restrict__ b3,
    float* __restrict__ out)
{
    __shared__ float sW1[4 * HID];
    __shared__ float sb1[HID];
    __shared__ float sW2T[HID * HID];
    __shared__ float sb2[HID];
    __shared__ float sw3[HID];
    for (int i = threadIdx.x; i < 4 * HID; i += 256) sW1[i] = W1[i];
    for (int i = threadIdx.x; i < HID; i += 256) {
        sb1[i] = b1[i]; sb2[i] = b2[i]; sw3[i] = W3[i * 5 + 4];
    }
    for (int idx = threadIdx.x; idx < HID * HID; idx += 256) {
        int jj = idx >> 5, ii = idx & 31;
        sW2T[idx] = W2[ii * HID + jj];
    }
    __syncthreads();

    int t = blockIdx.x * 256 + threadIdx.x;
    if (t >= T_TOTAL) return;

    float2 st = ((const float2*)traj)[t];
    float s0 = fmaxf(st.x, 0.0f);
    float s1 = fmaxf(st.y, 0.0f);
    float p  = inputs[t * 5 + 2];
    float tm = inputs[t * 5 + 3];

    float h1[HID];
#pragma unroll
    for (int jj = 0; jj < HID; ++jj) {
        float pre = fmaf(s0, sW1[jj], fmaf(s1, sW1[HID + jj],
                    fmaf(p, sW1[2 * HID + jj],
                    fmaf(tm, sW1[3 * HID + jj], sb1[jj]))));
        h1[jj] = fast_tanh_clamp(pre);
    }
    float o = b3[4];
#pragma unroll 4
    for (int jj = 0; jj < HID; ++jj) {
        float a0 = sb2[jj], a1 = 0.f, a2 = 0.f, a3 = 0.f;
#pragma unroll
        for (int ii = 0; ii < HID; ii += 4) {
            a0 = fmaf(h1[ii + 0], sW2T[jj * HID + ii + 0], a0);
            a1 = fmaf(h1[ii + 1], sW2T[jj * HID + ii + 1], a1);
            a2 = fmaf(h1[ii + 2], sW2T[jj * HID + ii + 2], a2);
            a3 = fmaf(h1[ii + 3], sW2T[jj * HID + ii + 3], a3);
        }
        o = fmaf(fast_tanh_nc((a0 + a1) + (a2 + a3)), sw3[jj], o);
    }
    out[t] = o;
}

extern "C" void kernel_launch(void* const* d_in, const int* in_sizes, int n_in,
                              void* d_out, int out_size, void* d_ws, size_t ws_size,
                              hipStream_t stream) {
    (void)in_sizes; (void)n_in; (void)out_size; (void)ws_size;
    const float* inputs = (const float*)d_in[0];
    const float* lday   = (const float*)d_in[1];
    const float* W1     = (const float*)d_in[2];
    const float* b1     = (const float*)d_in[3];
    const float* W2     = (const float*)d_in[4];
    const float* b2     = (const float*)d_in[5];
    const float* W3     = (const float*)d_in[6];
    const float* b3     = (const float*)d_in[7];
    float* out  = (float*)d_out;
    float* traj = (float*)d_ws;                 // T*2 floats = 2 MB

    // small Parareal arrays live in d_out (scratch until out_kernel, 1 MB)
    // E = 3*WIN double2 = 147456 B at offset 0; icg = WIN float2 = 24576 B
    // at offset 196608. Total 221184 <= 1 MB.
    char* scr = (char*)d_out;
    double2* E  = (double2*)scr;
    float2* icg = (float2*)(scr + 196608);

    hipLaunchKernelGGL(init_kernel, dim3((WIN + 255) / 256), dim3(256), 0, stream,
                       inputs, icg);
    for (int k = 0; k < NSWEEP - 1; ++k) {
        hipLaunchKernelGGL(sweep_kernel, dim3(WIN), dim3(64), 0, stream,
                           inputs, lday, W1, b1, W2, b2, W3, b3, traj, icg, E);
        hipLaunchKernelGGL(correct_kernel, dim3(1), dim3(128), 0, stream,
                           inputs, E, icg);
    }
    // final sweep: trajectory becomes self-consistent with corrected ICs
    hipLaunchKernelGGL(sweep_kernel, dim3(WIN), dim3(64), 0, stream,
                       inputs, lday, W1, b1, W2, b2, W3, b3, traj, icg, E);
    hipLaunchKernelGGL(out_kernel, dim3((T_TOTAL + 255) / 256), dim3(256), 0, stream,
                       inputs, traj, W1, b1, W2, b2, W3, b3, out);
}

// Round 13
// 2209.393 us; speedup vs baseline: 1.1432x; 1.1062x over previous
//
#include <hip/hip_runtime.h>
#include <math.h>

#define T_TOTAL 262144
#define HID 32
#define WIN 3072                      /* windows: 85-86 serial steps each */
/* window geometry: first 1024 windows have 86 steps, rest 85.
   S(w) = 85*w + min(w,1024); contiguous, covers [0, 262144). */
#define NSWEEP 6                      /* total sweeps; NSWEEP-1 corrections */
#define CH 1024                       /* correction chunk size (3 chunks) */
#define FD_EPS0 4.0                   /* FD perturbation on s0 (snow) */
#define FD_EPS1 8.0                   /* FD perturbation on s1 (water) */
#define LOG2E 1.4426950408889634f
#define TANH2C 2.8853900817779268f    /* 2*log2e */
#define NEG10LOG2E (-14.426950408889634f)
#define POS10LOG2E (14.426950408889634f)

#define PIN(x) asm volatile("" : "+v"(x))

typedef _Float16 f16x8 __attribute__((ext_vector_type(8)));
typedef float f32x4 __attribute__((ext_vector_type(4)));

__device__ __forceinline__ float fexp2(float x) { return __builtin_amdgcn_exp2f(x); }
__device__ __forceinline__ float frcp(float x)  { return __builtin_amdgcn_rcpf(x); }
__device__ __forceinline__ float fast_sig10(float x) {
    return frcp(1.0f + fexp2(x * NEG10LOG2E));
}
__device__ __forceinline__ float fast_tanh_clamp(float x) { // out_kernel only
    float xc = __builtin_amdgcn_fmed3f(x, -9.0f, 9.0f);
    float u  = fexp2(xc * TANH2C);
    return fmaf(-2.0f, frcp(u + 1.0f), 1.0f);
}
__device__ __forceinline__ float fast_tanh_nc(float x) {
    float u = fexp2(x * TANH2C);
    return fmaf(-2.0f, frcp(u + 1.0f), 1.0f);
}

// ---- DPP / lane helpers ----------------------------------------------------
template <int CTRL>
__device__ __forceinline__ float dpp_add(float v) {
    int t = __builtin_amdgcn_update_dpp(0, __float_as_int(v), CTRL, 0xF, 0xF, true);
    return v + __int_as_float(t);
}
__device__ __forceinline__ float allsum16(float x) {
    x = dpp_add<0xB1>(x);   // quad_perm xor1
    x = dpp_add<0x4E>(x);   // quad_perm xor2
    x = dpp_add<0x141>(x);  // row_half_mirror
    x = dpp_add<0x140>(x);  // row_mirror
    return x;
}
__device__ __forceinline__ int dpp_xor1_i(int v) {
    return __builtin_amdgcn_update_dpp(0, v, 0xB1, 0xF, 0xF, true);
}
__device__ __forceinline__ float rl(float x, int lane) {
    return __int_as_float(__builtin_amdgcn_readlane(__float_as_int(x), lane));
}
__device__ __forceinline__ float bpf(int addr, float x) {
    return __int_as_float(__builtin_amdgcn_ds_bpermute(addr, __float_as_int(x)));
}

// ---------------------------------------------------------------------------
// init: all window ICs = global Y0 guess (f32)
// ---------------------------------------------------------------------------
__global__ void init_kernel(const float* __restrict__ inputs, float2* icg) {
    int w = blockIdx.x * blockDim.x + threadIdx.x;
    if (w < WIN) icg[w] = make_float2(inputs[0], inputs[1]);
}

// ---------------------------------------------------------------------------
// Newton-Parareal sweep, FOUR trajectory slots per wave (3 used):
//   quad 0 = unperturbed, quad 1 = +FD_EPS0 on s0, quads 2,3 = +FD_EPS1 on s1.
// Structure validated R6-R12 (absmax at bf16 floor; ~305 us @ 3 waves/SIMD).
// Non-uniform windows: LEN = 86 for wnd<1024 else 85.
// UNCHANGED from R9.
// ---------------------------------------------------------------------------
__global__ __launch_bounds__(64, 1) void sweep_kernel(
    const float* __restrict__ inputs,   // (T,5)
    const float* __restrict__ lday,     // (T,)
    const float* __restrict__ W1, const float* __restrict__ b1,
    const float* __restrict__ W2, const float* __restrict__ b2,
    const float* __restrict__ W3, const float* __restrict__ b3,
    float* __restrict__ traj,           // (T,2)
    const float2* __restrict__ icg,     // window ICs (read, f32)
    double2* __restrict__ E)            // end states (write), 3*WIN
{
    const int lane = threadIdx.x;
    const int col  = lane & 15;
    const int quad = lane >> 4;
    const int j32  = lane & 31;
    const int half = lane >> 5;
    const bool odd = (lane & 1) != 0;

    const int wnd  = blockIdx.x;
    const int S    = wnd * 85 + ((wnd < 1024) ? wnd : 1024);
    const int LEN  = (wnd < 1024) ? 86 : 85;
    const int endStep = (S + LEN < T_TOTAL - 1) ? (S + LEN) : (T_TOTAL - 1);

    // layer-1 weights, pre-scaled by 2log2e
    float w1c0 = W1[0 * HID + j32] * TANH2C, w1c1 = W1[1 * HID + j32] * TANH2C;
    float w1c2 = W1[2 * HID + j32] * TANH2C, w1c3 = W1[3 * HID + j32] * TANH2C;
    float b1j = b1[j32] * TANH2C;
    PIN(w1c0); PIN(w1c1); PIN(w1c2); PIN(w1c3); PIN(b1j);

    // W2*2log2e as f16 hi/lo B-fragments
    f16x8 Bhi0, Blo0, Bhi1, Blo1;
#pragma unroll
    for (int jj = 0; jj < 8; ++jj) {
        float w0 = W2[(quad * 8 + jj) * HID + col] * TANH2C;
        float w1v = W2[(quad * 8 + jj) * HID + col + 16] * TANH2C;
        _Float16 h0 = (_Float16)w0, h1v = (_Float16)w1v;
        Bhi0[jj] = h0;  Blo0[jj] = (_Float16)(w0 - (float)h0);
        Bhi1[jj] = h1v; Blo1[jj] = (_Float16)(w1v - (float)h1v);
    }
    PIN(Bhi0); PIN(Blo0); PIN(Bhi1); PIN(Blo1);

    float b2a2 = b2[col] * TANH2C, b2b2 = b2[col + 16] * TANH2C;
    f32x4 cb0 = {b2a2, b2a2, b2a2, b2a2};
    f32x4 cb1 = {b2b2, b2b2, b2b2, b2b2};
    PIN(cb0); PIN(cb1);

    // layer-3 weights: 5 channels per 16-lane quad
    float wca[5], wcb[5];
#pragma unroll
    for (int c = 0; c < 5; ++c) {
        wca[c] = W3[col * 5 + c] * LOG2E;
        wcb[c] = W3[(col + 16) * 5 + c] * LOG2E;
        PIN(wca[c]); PIN(wcb[c]);
    }

    float m0 = (col == 0) ? 1.f : 0.f;
    float m1 = (col == 1) ? 1.f : 0.f;
    float m2 = (col == 2) ? 1.f : 0.f;
    float m3 = (col == 3) ? 1.f : 0.f;
    float m4 = (col == 4) ? 1.f : 0.f;
    float m5 = (col == 5) ? 1.f : 0.f;
    float m6 = (col == 6) ? 1.f : 0.f;
    float m7 = (col == 7) ? 1.f : 0.f;
    float m8 = (col == 8) ? 1.f : 0.f;
    float sig1m = (col >= 5 && col <= 8) ? 1.f : 0.f;
    float zb = b3[(col < 5) ? col : 0];
    float zconst = (col < 5) ? zb * LOG2E : 0.f;
    PIN(m0); PIN(m1); PIN(m2); PIN(m3); PIN(m4); PIN(m5); PIN(m6); PIN(m7); PIN(m8);
    PIN(sig1m); PIN(zconst);

    int psel = (lane & 1) ? 0x01000504 : 0x05040100;
    // A-build gather base by row class r&3: {A,B,C,C-dup} -> {+0,+128,+4,+132}
    int l3 = lane & 3;
    int roff = (l3 == 1) ? 128 : (l3 == 2) ? 4 : (l3 == 3) ? 132 : 0;
    int bbase = 32 * quad + roff;
    int bp0 = bbase, bp1 = bbase + 8, bp2 = bbase + 16, bp3 = bbase + 24;
    PIN(psel); PIN(bp0); PIN(bp1); PIN(bp2); PIN(bp3);

    // per-quad output-gather addresses (bytes)
    int qb = 64 * quad;
    int a_sh0 = qb + 0,  a_sh1 = qb + 4,  a_sh2 = qb + 8;
    int a_e3  = qb + 12, a_e4  = qb + 16, a_sg0 = qb + 20, a_sg1 = qb + 24;
    PIN(a_sh0); PIN(a_sh1); PIN(a_sh2); PIN(a_e3); PIN(a_e4); PIN(a_sg0); PIN(a_sg1);

    float2 ic = icg[wnd];
    double y0 = (double)ic.x + ((quad == 1) ? FD_EPS0 : 0.0);
    double y1 = (double)ic.y + ((quad >= 2) ? FD_EPS1 : 0.0);
    float2* traj2 = (float2*)traj;
    if (lane == 0 && wnd == 0)
        traj2[0] = make_float2(ic.x, ic.y);

    auto rhs = [&](float s0q, float s1q, float base, float stm, float ld, float zoffk,
                   float& d0, float& d1, float& rout) {
        // broadcast the three trajectory states for layer-1
        float s0A = rl(s0q, 0),  s1A = rl(s1q, 0);
        float s0B = rl(s0q, 16), s1B = rl(s1q, 16);
        float s0C = rl(s0q, 32), s1C = rl(s1q, 32);
        float s0p = half ? s0B : s0A;
        float s1p = half ? s1B : s1A;
        // layer-1: primary (A/B by half) and C (all lanes)
        float prep = fmaf(s1p, w1c1, fmaf(s0p, w1c0, base));
        float prec = fmaf(s1C, w1c1, fmaf(s0C, w1c0, base));
        float up_ = fexp2(prep);
        float uc_ = fexp2(prec);
        float h1p = fmaf(-2.0f, frcp(up_ + 1.0f), 1.0f);
        float h1c = fmaf(-2.0f, frcp(uc_ + 1.0f), 1.0f);
        union { _Float16 h; unsigned short u; } cvp, cvc;
        cvp.h = (_Float16)h1p; cvc.h = (_Float16)h1c;
        int ownp = (int)cvp.u, ownc = (int)cvc.u;
        int nbp = dpp_xor1_i(ownp), nbc = dpp_xor1_i(ownc);
        int pkp = __builtin_amdgcn_perm(nbp, ownp, psel);
        int pkc = __builtin_amdgcn_perm(nbc, ownc, psel);
        int pk  = odd ? pkc : pkp;
        int g0i = __builtin_amdgcn_ds_bpermute(bp0, pk);
        int g1i = __builtin_amdgcn_ds_bpermute(bp1, pk);
        int g2i = __builtin_amdgcn_ds_bpermute(bp2, pk);
        int g3i = __builtin_amdgcn_ds_bpermute(bp3, pk);
        union { int i[4]; f16x8 h; } au;
        au.i[0] = g0i; au.i[1] = g1i; au.i[2] = g2i; au.i[3] = g3i;
        f16x8 A = au.h;
        f32x4 zz = {0.f, 0.f, 0.f, 0.f};
        f32x4 chi0 = __builtin_amdgcn_mfma_f32_16x16x32_f16(A, Bhi0, cb0, 0, 0, 0);
        f32x4 clo0 = __builtin_amdgcn_mfma_f32_16x16x32_f16(A, Blo0, zz, 0, 0, 0);
        f32x4 chi1 = __builtin_amdgcn_mfma_f32_16x16x32_f16(A, Bhi1, cb1, 0, 0, 0);
        f32x4 clo1 = __builtin_amdgcn_mfma_f32_16x16x32_f16(A, Blo1, zz, 0, 0, 0);
        // per-quad trajectory row select (C rows: 4q+0=A, +1=B, +2=C, +3=C-dup)
        float tA0 = chi0[0] + clo0[0], tB0 = chi0[1] + clo0[1], tC0 = chi0[2] + clo0[2];
        float tA1 = chi1[0] + clo1[0], tB1 = chi1[1] + clo1[1], tC1 = chi1[2] + clo1[2];
        float t0 = (quad == 1) ? tB0 : (quad >= 2) ? tC0 : tA0;
        float t1 = (quad == 1) ? tB1 : (quad >= 2) ? tC1 : tA1;
        float ua = fexp2(t0);
        float ub = fexp2(t1);
        float g0 = fmaf(-2.0f, frcp(ua + 1.0f), 1.0f);
        float g1 = fmaf(-2.0f, frcp(ub + 1.0f), 1.0f);
        float r0 = fmaf(g0, wca[0], g1 * wcb[0]);
        float r1 = fmaf(g0, wca[1], g1 * wcb[1]);
        float r2 = fmaf(g0, wca[2], g1 * wcb[2]);
        float r3 = fmaf(g0, wca[3], g1 * wcb[3]);
        float r4 = fmaf(g0, wca[4], g1 * wcb[4]);
        float s0r = allsum16(r0);
        float s1r = allsum16(r1);
        float s2r = allsum16(r2);
        float s3r = allsum16(r3);
        float s4r = allsum16(r4);
        float zs0 = s0q * NEG10LOG2E;           // own quad's trajectory
        float zs1 = s1q * NEG10LOG2E;
        float zoff = fmaf(zs0, m5, fmaf(zs1, m6, zoffk));
        float zarg = fmaf(s0r, m0, fmaf(s1r, m1, fmaf(s2r, m2,
                     fmaf(s3r, m3, fmaf(s4r, m4, zoff)))));
        float u = fexp2(zarg);
        float r = frcp(u + sig1m);
        float w = fmaf(0.5f, u, -0.5f * r);
        float sh0 = bpf(a_sh0, w), sh1 = bpf(a_sh1, w), sh2 = bpf(a_sh2, w);
        float e3  = bpf(a_e3, u),  e4  = bpf(a_e4, u);
        float sg0 = bpf(a_sg0, r), sg1 = bpf(a_sg1, r);
        float p_snow = fmaxf(sh0 * stm, 0.f);
        float p_rain = fmaxf(sh1, 0.f);
        float melt   = fmaxf(sg0 * sh2, 0.f);
        float etq    = sg1 * fmaf(e3, ld, e4);
        d0 = p_snow - melt;
        d1 = (p_rain + melt) - etq;
        rout = r;
    };

    float pA = inputs[S * 5 + 2],       tmA = inputs[S * 5 + 3],       ldA = lday[S];
    float pB = inputs[(S + 1) * 5 + 2], tmB = inputs[(S + 1) * 5 + 3], ldB = lday[S + 1];
    float pC = inputs[(S + 2) * 5 + 2], tmC = inputs[(S + 2) * 5 + 3], ldC = lday[S + 2];
    float stmA = fast_sig10(-tmA);
    float stmB = fast_sig10(-tmB);
    float stmm = fast_sig10(-0.5f * (tmA + tmB));
    float baseA = fmaf(pA, w1c2, fmaf(tmA, w1c3, b1j));
    float baseB = fmaf(pB, w1c2, fmaf(tmB, w1c3, b1j));

    for (int n = S; n < endStep; ++n) {
        const float ldm = 0.5f * (ldA + ldB);
        const float pm  = 0.5f * (pA + pB);
        const float tmm = 0.5f * (tmA + tmB);
        const float basem = fmaf(pm, w1c2, fmaf(tmm, w1c3, b1j));
        const float ztm_m = (0.5f * (tmB + tmC)) * POS10LOG2E;
        const float ztm_b = tmC * POS10LOG2E;
        const float zoffk = fmaf(ztm_m, m7, fmaf(ztm_b, m8, zconst));

        const float fy0 = (float)y0, fy1 = (float)y1;
        float k10, k11, k20, k21, k30, k31, k40, k41, rd;
        rhs(fy0,                  fy1,                  baseA, stmA, ldA, zoffk, k10, k11, rd);
        rhs(fmaf(0.5f, k10, fy0), fmaf(0.5f, k11, fy1), basem, stmm, ldm, zoffk, k20, k21, rd);
        rhs(fmaf(0.5f, k20, fy0), fmaf(0.5f, k21, fy1), basem, stmm, ldm, zoffk, k30, k31, rd);
        rhs(fy0 + k30,            fy1 + k31,            baseB, stmB, ldB, zoffk, k40, k41, rd);
        const float stmm_n = rl(rd, 7);
        const float stmB_n = rl(rd, 8);

        const float s0sum = (k10 + 2.0f * k20) + (2.0f * k30 + k40);
        const float s1sum = (k11 + 2.0f * k21) + (2.0f * k31 + k41);
        y0 += (1.0 / 6.0) * (double)s0sum;
        y1 += (1.0 / 6.0) * (double)s1sum;

        if (lane == 0)
            traj2[n + 1] = make_float2((float)y0, (float)y1);

        stmA = stmB; stmB = stmB_n; stmm = stmm_n;
        baseA = baseB;
        baseB = fmaf(pC, w1c2, fmaf(tmC, w1c3, b1j));
        pA = pB; tmA = tmB; ldA = ldB;
        pB = pC; tmB = tmC; ldB = ldC;
        const int np3 = (n + 3 < T_TOTAL) ? (n + 3) : (T_TOTAL - 1);
        pC = inputs[np3 * 5 + 2]; tmC = inputs[np3 * 5 + 3]; ldC = lday[np3];
    }

    if (lane == 0)  E[wnd]           = make_double2(y0, y1);  // unperturbed
    if (lane == 16) E[WIN + wnd]     = make_double2(y0, y1);  // +eps0 on s0
    if (lane == 32) E[2 * WIN + wnd] = make_double2(y0, y1);  // +eps1 on s1
}

// ---------------------------------------------------------------------------
// Sequential Newton-Parareal correction — chunked double-buffered LDS,
// TWO WAVES (128 threads), serial loop UNROLLED x8.
// R12 post-mortem: the 2-wave split fixed the divergence serialization but
// the serial loop was still ~95 cyc/window — each iteration issued its 7
// LDS reads then waited lgkmcnt(0) (single-outstanding LDS latency in
// series with the f32 chain). R8's fast loop (29 cyc/window) had
// #pragma unroll 8: the compiler batches 56 independent ds_reads ahead of
// 8 chain steps, amortizing the latency. Restore it. Math unchanged.
// Clamps wide-open (R6-validated). J01 := 0.
// ---------------------------------------------------------------------------
__global__ __launch_bounds__(128) void correct_kernel(
    const float* __restrict__ inputs,
    const double2* __restrict__ E,
    float2* __restrict__ icg) {
    __shared__ float sJ00[2][CH], sJ10[2][CH], sJ11[2][CH];
    __shared__ float sE0x[2][CH], sE0y[2][CH];
    __shared__ float sGx[2][CH],  sGy[2][CH];     // 2*7*1024*4 = 57344 B
    const int tid = threadIdx.x;

    auto stage_one = [&](int buf, int i, int w) {
        double2 e0 = E[w];
        double2 e1 = E[WIN + w];
        double2 e2 = E[2 * WIN + w];
        float2 g   = icg[w];
        float J00 = (float)((e1.x - e0.x) * (1.0 / FD_EPS0));
        float J10 = (float)((e1.y - e0.y) * (1.0 / FD_EPS0));
        float J11 = (float)((e2.y - e0.y) * (1.0 / FD_EPS1));
        sJ00[buf][i] = fminf(fmaxf(J00, -0.15f), 1.15f);   // wide-open (R6)
        sJ10[buf][i] = fminf(fmaxf(J10, -0.30f), 1.80f);
        sJ11[buf][i] = fminf(fmaxf(J11,  0.00f), 1.10f);
        sE0x[buf][i] = (float)e0.x; sE0y[buf][i] = (float)e0.y;
        sGx[buf][i]  = g.x;         sGy[buf][i]  = g.y;
    };

    // prologue: all 128 threads stage chunk 0 into buffer 0
    for (int i = tid; i < CH; i += 128) stage_one(0, i, i);
    __syncthreads();

    float y0c = inputs[0];
    float y1c = inputs[1];
    for (int c = 0; c < 3; ++c) {
        const int buf = c & 1;
        if (tid == 0) {
            // wave 0: serial recurrence over chunk c — LDS reads +
            // fire-and-forget global stores only (vmcnt never waited).
            // unroll 8 batches the LDS reads ahead of the chain (R8 recipe).
            const int wbase = c * CH;
#pragma unroll 8
            for (int i = 0; i < CH; ++i) {
                float d0 = y0c - sGx[buf][i];
                float d1 = y1c - sGy[buf][i];
                d0 = fminf(fmaxf(d0, -50.0f), 50.0f);      // trust region
                d1 = fminf(fmaxf(d1, -400.0f), 400.0f);
                icg[wbase + i] = make_float2(y0c, y1c);    // fire-and-forget
                y0c = fmaf(sJ00[buf][i], d0, sE0x[buf][i]);        // J01 = 0
                y1c = fmaf(sJ10[buf][i], d0, fmaf(sJ11[buf][i], d1, sE0y[buf][i]));
                y0c = fminf(fmaxf(y0c, -5.0f), 1000.0f);   // physical sanity
                y1c = fminf(fmaxf(y1c, -5.0f), 5000.0f);
            }
        } else if (tid >= 64 && c + 1 < 3) {
            // wave 1: stage chunk c+1 into the other buffer, truly overlapped
            for (int i = tid - 64; i < CH; i += 64)
                stage_one((c + 1) & 1, i, (c + 1) * CH + i);
        }
        __syncthreads();
    }
}

// ---------------------------------------------------------------------------
// Parallel readout: out[t] = mlp(relu(state), p, tm)[4]
// ---------------------------------------------------------------------------
__global__ __launch_bounds__(256) void out_kernel(
    const float* __restrict__ inputs,
    const float* __restrict__ traj,
    const float* __restrict__ W1, const float* __restrict__ b1,
    const float* __restrict__ W2, const float* __restrict__ b2,
    const float* __restrict__ W3, const float* __restrict__ b3,
    float* __restrict__ out)
{
    __shared__ float sW1[4 * HID];
    __shared__ float sb1[HID];
    __shared__ float sW2T[HID * HID];
    __shared__ float sb2[HID];
    __shared__ float sw3[HID];
    for (int i = threadIdx.x; i < 4 * HID; i += 256) sW1[i] = W1[i];
    for (int i = threadIdx.x; i < HID; i += 256) {
        sb1[i] = b1[i]; sb2[i] = b2[i]; sw3[i] = W3[i * 5 + 4];
    }
    for (int idx = threadIdx.x; idx < HID * HID; idx += 256) {
        int jj = idx >> 5, ii = idx & 31;
        sW2T[idx] = W2[ii * HID + jj];
    }
    __syncthreads();

    int t = blockIdx.x * 256 + threadIdx.x;
    if (t >= T_TOTAL) return;

    float2 st = ((const float2*)traj)[t];
    float s0 = fmaxf(st.x, 0.0f);
    float s1 = fmaxf(st.y, 0.0f);
    float p  = inputs[t * 5 + 2];
    float tm = inputs[t * 5 + 3];

    float h1[HID];
#pragma unroll
    for (int jj = 0; jj < HID; ++jj) {
        float pre = fmaf(s0, sW1[jj], fmaf(s1, sW1[HID + jj],
                    fmaf(p, sW1[2 * HID + jj],
                    fmaf(tm, sW1[3 * HID + jj], sb1[jj]))));
        h1[jj] = fast_tanh_clamp(pre);
    }
    float o = b3[4];
#pragma unroll 4
    for (int jj = 0; jj < HID; ++jj) {
        float a0 = sb2[jj], a1 = 0.f, a2 = 0.f, a3 = 0.f;
#pragma unroll
        for (int ii = 0; ii < HID; ii += 4) {
            a0 = fmaf(h1[ii + 0], sW2T[jj * HID + ii + 0], a0);
            a1 = fmaf(h1[ii + 1], sW2T[jj * HID + ii + 1], a1);
            a2 = fmaf(h1[ii + 2], sW2T[jj * HID + ii + 2], a2);
            a3 = fmaf(h1[ii + 3], sW2T[jj * HID + ii + 3], a3);
        }
        o = fmaf(fast_tanh_nc((a0 + a1) + (a2 + a3)), sw3[jj], o);
    }
    out[t] = o;
}

extern "C" void kernel_launch(void* const* d_in, const int* in_sizes, int n_in,
                              void* d_out, int out_size, void* d_ws, size_t ws_size,
                              hipStream_t stream) {
    (void)in_sizes; (void)n_in; (void)out_size; (void)ws_size;
    const float* inputs = (const float*)d_in[0];
    const float* lday   = (const float*)d_in[1];
    const float* W1     = (const float*)d_in[2];
    const float* b1     = (const float*)d_in[3];
    const float* W2     = (const float*)d_in[4];
    const float* b2     = (const float*)d_in[5];
    const float* W3     = (const float*)d_in[6];
    const float* b3     = (const float*)d_in[7];
    float* out  = (float*)d_out;
    float* traj = (float*)d_ws;                 // T*2 floats = 2 MB

    // small Parareal arrays live in d_out (scratch until out_kernel, 1 MB)
    // E = 3*WIN double2 = 147456 B at offset 0; icg = WIN float2 = 24576 B
    // at offset 196608. Total 221184 <= 1 MB.
    char* scr = (char*)d_out;
    double2* E  = (double2*)scr;
    float2* icg = (float2*)(scr + 196608);

    hipLaunchKernelGGL(init_kernel, dim3((WIN + 255) / 256), dim3(256), 0, stream,
                       inputs, icg);
    for (int k = 0; k < NSWEEP - 1; ++k) {
        hipLaunchKernelGGL(sweep_kernel, dim3(WIN), dim3(64), 0, stream,
                           inputs, lday, W1, b1, W2, b2, W3, b3, traj, icg, E);
        hipLaunchKernelGGL(correct_kernel, dim3(1), dim3(128), 0, stream,
                           inputs, E, icg);
    }
    // final sweep: trajectory becomes self-consistent with corrected ICs
    hipLaunchKernelGGL(sweep_kernel, dim3(WIN), dim3(64), 0, stream,
                       inputs, lday, W1, b1, W2, b2, W3, b3, traj, icg, E);
    hipLaunchKernelGGL(out_kernel, dim3((T_TOTAL + 255) / 256), dim3(256), 0, stream,
                       inputs, traj, W1, b1, W2, b2, W3, b3, out);
}

// Round 14
// 2034.408 us; speedup vs baseline: 1.2415x; 1.0860x over previous
//
#include <hip/hip_runtime.h>
#include <math.h>

#define T_TOTAL 262144
#define HID 32
#define WIN 3072                      /* windows: 85-86 serial steps each */
/* window geometry: first 1024 windows have 86 steps, rest 85.
   S(w) = 85*w + min(w,1024); contiguous, covers [0, 262144). */
#define NSWEEP 5                      /* total sweeps; NSWEEP-1 corrections */
#define CH 1024                       /* correction chunk size (3 chunks) */
#define FD_EPS0 4.0                   /* FD perturbation on s0 (snow) */
#define FD_EPS1 8.0                   /* FD perturbation on s1 (water), quad 2 */
#define FD_EPS1B 4.0                  /* FD perturbation on s1, quad 3 (Richardson) */
#define LOG2E 1.4426950408889634f
#define TANH2C 2.8853900817779268f    /* 2*log2e */
#define NEG10LOG2E (-14.426950408889634f)
#define POS10LOG2E (14.426950408889634f)

#define PIN(x) asm volatile("" : "+v"(x))

typedef _Float16 f16x8 __attribute__((ext_vector_type(8)));
typedef float f32x4 __attribute__((ext_vector_type(4)));

__device__ __forceinline__ float fexp2(float x) { return __builtin_amdgcn_exp2f(x); }
__device__ __forceinline__ float frcp(float x)  { return __builtin_amdgcn_rcpf(x); }
__device__ __forceinline__ float fast_sig10(float x) {
    return frcp(1.0f + fexp2(x * NEG10LOG2E));
}
__device__ __forceinline__ float fast_tanh_clamp(float x) { // out_kernel only
    float xc = __builtin_amdgcn_fmed3f(x, -9.0f, 9.0f);
    float u  = fexp2(xc * TANH2C);
    return fmaf(-2.0f, frcp(u + 1.0f), 1.0f);
}
__device__ __forceinline__ float fast_tanh_nc(float x) {
    float u = fexp2(x * TANH2C);
    return fmaf(-2.0f, frcp(u + 1.0f), 1.0f);
}

// ---- DPP / lane helpers ----------------------------------------------------
template <int CTRL>
__device__ __forceinline__ float dpp_add(float v) {
    int t = __builtin_amdgcn_update_dpp(0, __float_as_int(v), CTRL, 0xF, 0xF, true);
    return v + __int_as_float(t);
}
__device__ __forceinline__ float allsum16(float x) {
    x = dpp_add<0xB1>(x);   // quad_perm xor1
    x = dpp_add<0x4E>(x);   // quad_perm xor2
    x = dpp_add<0x141>(x);  // row_half_mirror
    x = dpp_add<0x140>(x);  // row_mirror
    return x;
}
__device__ __forceinline__ int dpp_xor1_i(int v) {
    return __builtin_amdgcn_update_dpp(0, v, 0xB1, 0xF, 0xF, true);
}
__device__ __forceinline__ float rl(float x, int lane) {
    return __int_as_float(__builtin_amdgcn_readlane(__float_as_int(x), lane));
}
__device__ __forceinline__ float bpf(int addr, float x) {
    return __int_as_float(__builtin_amdgcn_ds_bpermute(addr, __float_as_int(x)));
}

// ---------------------------------------------------------------------------
// init: all window ICs = global Y0 guess (f32)
// ---------------------------------------------------------------------------
__global__ void init_kernel(const float* __restrict__ inputs, float2* icg) {
    int w = blockIdx.x * blockDim.x + threadIdx.x;
    if (w < WIN) icg[w] = make_float2(inputs[0], inputs[1]);
}

// ---------------------------------------------------------------------------
// Newton-Parareal sweep, FOUR REAL trajectories per wave:
//   quad 0 = unperturbed, quad 1 = +FD_EPS0 on s0,
//   quad 2 = +FD_EPS1 (8) on s1, quad 3 = +FD_EPS1B (4) on s1.
// Quad 3 (previously a duplicate of quad 2) now carries a second water
// perturbation so the correction can Richardson-extrapolate J11 =
// 2*S(4) - S(8), cancelling the O(eps) secant error on the dominant
// (water, J11~1) error mode. Layer-1 computes h1 for: primary (A/B by
// half), C (all lanes), D (all lanes); packed f16 words: A at even
// half-0 lanes, B at even half-1, C at odd half-0, D at odd half-1.
// A-fragment row class r&3 {0,1,2,3} gathers from {+0,+128,+4,+132}.
// Unperturbed path unchanged from R9-R13 (validated at bf16 floor).
// Non-uniform windows: LEN = 86 for wnd<1024 else 85.
// ---------------------------------------------------------------------------
__global__ __launch_bounds__(64, 1) void sweep_kernel(
    const float* __restrict__ inputs,   // (T,5)
    const float* __restrict__ lday,     // (T,)
    const float* __restrict__ W1, const float* __restrict__ b1,
    const float* __restrict__ W2, const float* __restrict__ b2,
    const float* __restrict__ W3, const float* __restrict__ b3,
    float* __restrict__ traj,           // (T,2)
    const float2* __restrict__ icg,     // window ICs (read, f32)
    double2* __restrict__ E)            // end states (write), 4*WIN
{
    const int lane = threadIdx.x;
    const int col  = lane & 15;
    const int quad = lane >> 4;
    const int j32  = lane & 31;
    const int half = lane >> 5;
    const bool odd = (lane & 1) != 0;

    const int wnd  = blockIdx.x;
    const int S    = wnd * 85 + ((wnd < 1024) ? wnd : 1024);
    const int LEN  = (wnd < 1024) ? 86 : 85;
    const int endStep = (S + LEN < T_TOTAL - 1) ? (S + LEN) : (T_TOTAL - 1);

    // layer-1 weights, pre-scaled by 2log2e
    float w1c0 = W1[0 * HID + j32] * TANH2C, w1c1 = W1[1 * HID + j32] * TANH2C;
    float w1c2 = W1[2 * HID + j32] * TANH2C, w1c3 = W1[3 * HID + j32] * TANH2C;
    float b1j = b1[j32] * TANH2C;
    PIN(w1c0); PIN(w1c1); PIN(w1c2); PIN(w1c3); PIN(b1j);

    // W2*2log2e as f16 hi/lo B-fragments
    f16x8 Bhi0, Blo0, Bhi1, Blo1;
#pragma unroll
    for (int jj = 0; jj < 8; ++jj) {
        float w0 = W2[(quad * 8 + jj) * HID + col] * TANH2C;
        float w1v = W2[(quad * 8 + jj) * HID + col + 16] * TANH2C;
        _Float16 h0 = (_Float16)w0, h1v = (_Float16)w1v;
        Bhi0[jj] = h0;  Blo0[jj] = (_Float16)(w0 - (float)h0);
        Bhi1[jj] = h1v; Blo1[jj] = (_Float16)(w1v - (float)h1v);
    }
    PIN(Bhi0); PIN(Blo0); PIN(Bhi1); PIN(Blo1);

    float b2a2 = b2[col] * TANH2C, b2b2 = b2[col + 16] * TANH2C;
    f32x4 cb0 = {b2a2, b2a2, b2a2, b2a2};
    f32x4 cb1 = {b2b2, b2b2, b2b2, b2b2};
    PIN(cb0); PIN(cb1);

    // layer-3 weights: 5 channels per 16-lane quad
    float wca[5], wcb[5];
#pragma unroll
    for (int c = 0; c < 5; ++c) {
        wca[c] = W3[col * 5 + c] * LOG2E;
        wcb[c] = W3[(col + 16) * 5 + c] * LOG2E;
        PIN(wca[c]); PIN(wcb[c]);
    }

    float m0 = (col == 0) ? 1.f : 0.f;
    float m1 = (col == 1) ? 1.f : 0.f;
    float m2 = (col == 2) ? 1.f : 0.f;
    float m3 = (col == 3) ? 1.f : 0.f;
    float m4 = (col == 4) ? 1.f : 0.f;
    float m5 = (col == 5) ? 1.f : 0.f;
    float m6 = (col == 6) ? 1.f : 0.f;
    float m7 = (col == 7) ? 1.f : 0.f;
    float m8 = (col == 8) ? 1.f : 0.f;
    float sig1m = (col >= 5 && col <= 8) ? 1.f : 0.f;
    float zb = b3[(col < 5) ? col : 0];
    float zconst = (col < 5) ? zb * LOG2E : 0.f;
    PIN(m0); PIN(m1); PIN(m2); PIN(m3); PIN(m4); PIN(m5); PIN(m6); PIN(m7); PIN(m8);
    PIN(sig1m); PIN(zconst);

    int psel = (lane & 1) ? 0x01000504 : 0x05040100;
    // A-build gather base by row class r&3: {A,B,C,D} -> {+0,+128,+4,+132}
    int l3 = lane & 3;
    int roff = (l3 == 1) ? 128 : (l3 == 2) ? 4 : (l3 == 3) ? 132 : 0;
    int bbase = 32 * quad + roff;
    int bp0 = bbase, bp1 = bbase + 8, bp2 = bbase + 16, bp3 = bbase + 24;
    PIN(psel); PIN(bp0); PIN(bp1); PIN(bp2); PIN(bp3);

    // per-quad output-gather addresses (bytes)
    int qb = 64 * quad;
    int a_sh0 = qb + 0,  a_sh1 = qb + 4,  a_sh2 = qb + 8;
    int a_e3  = qb + 12, a_e4  = qb + 16, a_sg0 = qb + 20, a_sg1 = qb + 24;
    PIN(a_sh0); PIN(a_sh1); PIN(a_sh2); PIN(a_e3); PIN(a_e4); PIN(a_sg0); PIN(a_sg1);

    float2 ic = icg[wnd];
    double y0 = (double)ic.x + ((quad == 1) ? FD_EPS0 : 0.0);
    double y1 = (double)ic.y +
                ((quad == 2) ? FD_EPS1 : (quad == 3) ? FD_EPS1B : 0.0);
    float2* traj2 = (float2*)traj;
    if (lane == 0 && wnd == 0)
        traj2[0] = make_float2(ic.x, ic.y);

    auto rhs = [&](float s0q, float s1q, float base, float stm, float ld, float zoffk,
                   float& d0, float& d1, float& rout) {
        // broadcast the four trajectory states for layer-1
        float s0A = rl(s0q, 0),  s1A = rl(s1q, 0);
        float s0B = rl(s0q, 16), s1B = rl(s1q, 16);
        float s0C = rl(s0q, 32), s1C = rl(s1q, 32);
        float s0D = rl(s0q, 48), s1D = rl(s1q, 48);
        float s0p = half ? s0B : s0A;
        float s1p = half ? s1B : s1A;
        // layer-1: primary (A/B by half), C and D (all lanes)
        float prep = fmaf(s1p, w1c1, fmaf(s0p, w1c0, base));
        float prec = fmaf(s1C, w1c1, fmaf(s0C, w1c0, base));
        float pred = fmaf(s1D, w1c1, fmaf(s0D, w1c0, base));
        float up_ = fexp2(prep);
        float uc_ = fexp2(prec);
        float ud_ = fexp2(pred);
        float h1p = fmaf(-2.0f, frcp(up_ + 1.0f), 1.0f);
        float h1c = fmaf(-2.0f, frcp(uc_ + 1.0f), 1.0f);
        float h1d = fmaf(-2.0f, frcp(ud_ + 1.0f), 1.0f);
        union { _Float16 h; unsigned short u; } cvp, cvc, cvd;
        cvp.h = (_Float16)h1p; cvc.h = (_Float16)h1c; cvd.h = (_Float16)h1d;
        int ownp = (int)cvp.u, ownc = (int)cvc.u, ownd = (int)cvd.u;
        int nbp = dpp_xor1_i(ownp), nbc = dpp_xor1_i(ownc), nbd = dpp_xor1_i(ownd);
        int pkp = __builtin_amdgcn_perm(nbp, ownp, psel);
        int pkc = __builtin_amdgcn_perm(nbc, ownc, psel);
        int pkd = __builtin_amdgcn_perm(nbd, ownd, psel);
        // packed words: A=even half0, B=even half1, C=odd half0, D=odd half1
        int pk  = odd ? (half ? pkd : pkc) : pkp;
        int g0i = __builtin_amdgcn_ds_bpermute(bp0, pk);
        int g1i = __builtin_amdgcn_ds_bpermute(bp1, pk);
        int g2i = __builtin_amdgcn_ds_bpermute(bp2, pk);
        int g3i = __builtin_amdgcn_ds_bpermute(bp3, pk);
        union { int i[4]; f16x8 h; } au;
        au.i[0] = g0i; au.i[1] = g1i; au.i[2] = g2i; au.i[3] = g3i;
        f16x8 A = au.h;
        f32x4 zz = {0.f, 0.f, 0.f, 0.f};
        f32x4 chi0 = __builtin_amdgcn_mfma_f32_16x16x32_f16(A, Bhi0, cb0, 0, 0, 0);
        f32x4 clo0 = __builtin_amdgcn_mfma_f32_16x16x32_f16(A, Blo0, zz, 0, 0, 0);
        f32x4 chi1 = __builtin_amdgcn_mfma_f32_16x16x32_f16(A, Bhi1, cb1, 0, 0, 0);
        f32x4 clo1 = __builtin_amdgcn_mfma_f32_16x16x32_f16(A, Blo1, zz, 0, 0, 0);
        // per-quad trajectory row select (C rows: 4q+0=A, +1=B, +2=C, +3=D)
        float tA0 = chi0[0] + clo0[0], tB0 = chi0[1] + clo0[1];
        float tC0 = chi0[2] + clo0[2], tD0 = chi0[3] + clo0[3];
        float tA1 = chi1[0] + clo1[0], tB1 = chi1[1] + clo1[1];
        float tC1 = chi1[2] + clo1[2], tD1 = chi1[3] + clo1[3];
        float t0 = (quad == 0) ? tA0 : (quad == 1) ? tB0 : (quad == 2) ? tC0 : tD0;
        float t1 = (quad == 0) ? tA1 : (quad == 1) ? tB1 : (quad == 2) ? tC1 : tD1;
        float ua = fexp2(t0);
        float ub = fexp2(t1);
        float g0 = fmaf(-2.0f, frcp(ua + 1.0f), 1.0f);
        float g1 = fmaf(-2.0f, frcp(ub + 1.0f), 1.0f);
        float r0 = fmaf(g0, wca[0], g1 * wcb[0]);
        float r1 = fmaf(g0, wca[1], g1 * wcb[1]);
        float r2 = fmaf(g0, wca[2], g1 * wcb[2]);
        float r3 = fmaf(g0, wca[3], g1 * wcb[3]);
        float r4 = fmaf(g0, wca[4], g1 * wcb[4]);
        float s0r = allsum16(r0);
        float s1r = allsum16(r1);
        float s2r = allsum16(r2);
        float s3r = allsum16(r3);
        float s4r = allsum16(r4);
        float zs0 = s0q * NEG10LOG2E;           // own quad's trajectory
        float zs1 = s1q * NEG10LOG2E;
        float zoff = fmaf(zs0, m5, fmaf(zs1, m6, zoffk));
        float zarg = fmaf(s0r, m0, fmaf(s1r, m1, fmaf(s2r, m2,
                     fmaf(s3r, m3, fmaf(s4r, m4, zoff)))));
        float u = fexp2(zarg);
        float r = frcp(u + sig1m);
        float w = fmaf(0.5f, u, -0.5f * r);
        float sh0 = bpf(a_sh0, w), sh1 = bpf(a_sh1, w), sh2 = bpf(a_sh2, w);
        float e3  = bpf(a_e3, u),  e4  = bpf(a_e4, u);
        float sg0 = bpf(a_sg0, r), sg1 = bpf(a_sg1, r);
        float p_snow = fmaxf(sh0 * stm, 0.f);
        float p_rain = fmaxf(sh1, 0.f);
        float melt   = fmaxf(sg0 * sh2, 0.f);
        float etq    = sg1 * fmaf(e3, ld, e4);
        d0 = p_snow - melt;
        d1 = (p_rain + melt) - etq;
        rout = r;
    };

    float pA = inputs[S * 5 + 2],       tmA = inputs[S * 5 + 3],       ldA = lday[S];
    float pB = inputs[(S + 1) * 5 + 2], tmB = inputs[(S + 1) * 5 + 3], ldB = lday[S + 1];
    float pC = inputs[(S + 2) * 5 + 2], tmC = inputs[(S + 2) * 5 + 3], ldC = lday[S + 2];
    float stmA = fast_sig10(-tmA);
    float stmB = fast_sig10(-tmB);
    float stmm = fast_sig10(-0.5f * (tmA + tmB));
    float baseA = fmaf(pA, w1c2, fmaf(tmA, w1c3, b1j));
    float baseB = fmaf(pB, w1c2, fmaf(tmB, w1c3, b1j));

    for (int n = S; n < endStep; ++n) {
        const float ldm = 0.5f * (ldA + ldB);
        const float pm  = 0.5f * (pA + pB);
        const float tmm = 0.5f * (tmA + tmB);
        const float basem = fmaf(pm, w1c2, fmaf(tmm, w1c3, b1j));
        const float ztm_m = (0.5f * (tmB + tmC)) * POS10LOG2E;
        const float ztm_b = tmC * POS10LOG2E;
        const float zoffk = fmaf(ztm_m, m7, fmaf(ztm_b, m8, zconst));

        const float fy0 = (float)y0, fy1 = (float)y1;
        float k10, k11, k20, k21, k30, k31, k40, k41, rd;
        rhs(fy0,                  fy1,                  baseA, stmA, ldA, zoffk, k10, k11, rd);
        rhs(fmaf(0.5f, k10, fy0), fmaf(0.5f, k11, fy1), basem, stmm, ldm, zoffk, k20, k21, rd);
        rhs(fmaf(0.5f, k20, fy0), fmaf(0.5f, k21, fy1), basem, stmm, ldm, zoffk, k30, k31, rd);
        rhs(fy0 + k30,            fy1 + k31,            baseB, stmB, ldB, zoffk, k40, k41, rd);
        const float stmm_n = rl(rd, 7);
        const float stmB_n = rl(rd, 8);

        const float s0sum = (k10 + 2.0f * k20) + (2.0f * k30 + k40);
        const float s1sum = (k11 + 2.0f * k21) + (2.0f * k31 + k41);
        y0 += (1.0 / 6.0) * (double)s0sum;
        y1 += (1.0 / 6.0) * (double)s1sum;

        if (lane == 0)
            traj2[n + 1] = make_float2((float)y0, (float)y1);

        stmA = stmB; stmB = stmB_n; stmm = stmm_n;
        baseA = baseB;
        baseB = fmaf(pC, w1c2, fmaf(tmC, w1c3, b1j));
        pA = pB; tmA = tmB; ldA = ldB;
        pB = pC; tmB = tmC; ldB = ldC;
        const int np3 = (n + 3 < T_TOTAL) ? (n + 3) : (T_TOTAL - 1);
        pC = inputs[np3 * 5 + 2]; tmC = inputs[np3 * 5 + 3]; ldC = lday[np3];
    }

    if (lane == 0)  E[wnd]           = make_double2(y0, y1);  // unperturbed
    if (lane == 16) E[WIN + wnd]     = make_double2(y0, y1);  // +eps0 on s0
    if (lane == 32) E[2 * WIN + wnd] = make_double2(y0, y1);  // +8 on s1
    if (lane == 48) E[3 * WIN + wnd] = make_double2(y0, y1);  // +4 on s1
}

// ---------------------------------------------------------------------------
// Sequential Newton-Parareal correction — chunked double-buffered LDS,
// TWO WAVES (128 threads), serial loop UNROLLED x8 (R13-validated: ~64 us).
// NEW: J11 by Richardson extrapolation, J11 = 2*S(4) - S(8) where
// S(h) = (E(+h)-E0)/h — cancels the O(eps) secant error on the dominant
// water mode, buying contraction so 4 corrections suffice (NSWEEP=5).
// Clamps wide-open (R6-validated). J01 := 0.
// ---------------------------------------------------------------------------
__global__ __launch_bounds__(128) void correct_kernel(
    const float* __restrict__ inputs,
    const double2* __restrict__ E,
    float2* __restrict__ icg) {
    __shared__ float sJ00[2][CH], sJ10[2][CH], sJ11[2][CH];
    __shared__ float sE0x[2][CH], sE0y[2][CH];
    __shared__ float sGx[2][CH],  sGy[2][CH];     // 2*7*1024*4 = 57344 B
    const int tid = threadIdx.x;

    auto stage_one = [&](int buf, int i, int w) {
        double2 e0 = E[w];
        double2 e1 = E[WIN + w];
        double2 e2 = E[2 * WIN + w];
        double2 e3 = E[3 * WIN + w];
        float2 g   = icg[w];
        float J00 = (float)((e1.x - e0.x) * (1.0 / FD_EPS0));
        float J10 = (float)((e1.y - e0.y) * (1.0 / FD_EPS0));
        // Richardson: 2*(E(+4)-E0)/4 - (E(+8)-E0)/8
        float J11 = (float)((e3.y - e0.y) * (2.0 / FD_EPS1B)
                          - (e2.y - e0.y) * (1.0 / FD_EPS1));
        sJ00[buf][i] = fminf(fmaxf(J00, -0.15f), 1.15f);   // wide-open (R6)
        sJ10[buf][i] = fminf(fmaxf(J10, -0.30f), 1.80f);
        sJ11[buf][i] = fminf(fmaxf(J11,  0.00f), 1.10f);
        sE0x[buf][i] = (float)e0.x; sE0y[buf][i] = (float)e0.y;
        sGx[buf][i]  = g.x;         sGy[buf][i]  = g.y;
    };

    // prologue: all 128 threads stage chunk 0 into buffer 0
    for (int i = tid; i < CH; i += 128) stage_one(0, i, i);
    __syncthreads();

    float y0c = inputs[0];
    float y1c = inputs[1];
    for (int c = 0; c < 3; ++c) {
        const int buf = c & 1;
        if (tid == 0) {
            // wave 0: serial recurrence over chunk c — LDS reads +
            // fire-and-forget global stores only; unroll 8 batches the
            // LDS reads ahead of the f32 chain (R8/R13 recipe).
            const int wbase = c * CH;
#pragma unroll 8
            for (int i = 0; i < CH; ++i) {
                float d0 = y0c - sGx[buf][i];
                float d1 = y1c - sGy[buf][i];
                d0 = fminf(fmaxf(d0, -50.0f), 50.0f);      // trust region
                d1 = fminf(fmaxf(d1, -400.0f), 400.0f);
                icg[wbase + i] = make_float2(y0c, y1c);    // fire-and-forget
                y0c = fmaf(sJ00[buf][i], d0, sE0x[buf][i]);        // J01 = 0
                y1c = fmaf(sJ10[buf][i], d0, fmaf(sJ11[buf][i], d1, sE0y[buf][i]));
                y0c = fminf(fmaxf(y0c, -5.0f), 1000.0f);   // physical sanity
                y1c = fminf(fmaxf(y1c, -5.0f), 5000.0f);
            }
        } else if (tid >= 64 && c + 1 < 3) {
            // wave 1: stage chunk c+1 into the other buffer, truly overlapped
            for (int i = tid - 64; i < CH; i += 64)
                stage_one((c + 1) & 1, i, (c + 1) * CH + i);
        }
        __syncthreads();
    }
}

// ---------------------------------------------------------------------------
// Parallel readout: out[t] = mlp(relu(state), p, tm)[4]
// ---------------------------------------------------------------------------
__global__ __launch_bounds__(256) void out_kernel(
    const float* __restrict__ inputs,
    const float* __restrict__ traj,
    const float* __restrict__ W1, const float* __restrict__ b1,
    const float* __restrict__ W2, const float* __restrict__ b2,
    const float* __restrict__ W3, const float* __restrict__ b3,
    float* __restrict__ out)
{
    __shared__ float sW1[4 * HID];
    __shared__ float sb1[HID];
    __shared__ float sW2T[HID * HID];
    __shared__ float sb2[HID];
    __shared__ float sw3[HID];
    for (int i = threadIdx.x; i < 4 * HID; i += 256) sW1[i] = W1[i];
    for (int i = threadIdx.x; i < HID; i += 256) {
        sb1[i] = b1[i]; sb2[i] = b2[i]; sw3[i] = W3[i * 5 + 4];
    }
    for (int idx = threadIdx.x; idx < HID * HID; idx += 256) {
        int jj = idx >> 5, ii = idx & 31;
        sW2T[idx] = W2[ii * HID + jj];
    }
    __syncthreads();

    int t = blockIdx.x * 256 + threadIdx.x;
    if (t >= T_TOTAL) return;

    float2 st = ((const float2*)traj)[t];
    float s0 = fmaxf(st.x, 0.0f);
    float s1 = fmaxf(st.y, 0.0f);
    float p  = inputs[t * 5 + 2];
    float tm = inputs[t * 5 + 3];

    float h1[HID];
#pragma unroll
    for (int jj = 0; jj < HID; ++jj) {
        float pre = fmaf(s0, sW1[jj], fmaf(s1, sW1[HID + jj],
                    fmaf(p, sW1[2 * HID + jj],
                    fmaf(tm, sW1[3 * HID + jj], sb1[jj]))));
        h1[jj] = fast_tanh_clamp(pre);
    }
    float o = b3[4];
#pragma unroll 4
    for (int jj = 0; jj < HID; ++jj) {
        float a0 = sb2[jj], a1 = 0.f, a2 = 0.f, a3 = 0.f;
#pragma unroll
        for (int ii = 0; ii < HID; ii += 4) {
            a0 = fmaf(h1[ii + 0], sW2T[jj * HID + ii + 0], a0);
            a1 = fmaf(h1[ii + 1], sW2T[jj * HID + ii + 1], a1);
            a2 = fmaf(h1[ii + 2], sW2T[jj * HID + ii + 2], a2);
            a3 = fmaf(h1[ii + 3], sW2T[jj * HID + ii + 3], a3);
        }
        o = fmaf(fast_tanh_nc((a0 + a1) + (a2 + a3)), sw3[jj], o);
    }
    out[t] = o;
}

extern "C" void kernel_launch(void* const* d_in, const int* in_sizes, int n_in,
                              void* d_out, int out_size, void* d_ws, size_t ws_size,
                              hipStream_t stream) {
    (void)in_sizes; (void)n_in; (void)out_size; (void)ws_size;
    const float* inputs = (const float*)d_in[0];
    const float* lday   = (const float*)d_in[1];
    const float* W1     = (const float*)d_in[2];
    const float* b1     = (const float*)d_in[3];
    const float* W2     = (const float*)d_in[4];
    const float* b2     = (const float*)d_in[5];
    const float* W3     = (const float*)d_in[6];
    const float* b3     = (const float*)d_in[7];
    float* out  = (float*)d_out;
    float* traj = (float*)d_ws;                 // T*2 floats = 2 MB

    // small Parareal arrays live in d_out (scratch until out_kernel, 1 MB)
    // E = 4*WIN double2 = 196608 B at offset 0; icg = WIN float2 = 24576 B
    // at offset 262144. Total 286720 <= 1 MB.
    char* scr = (char*)d_out;
    double2* E  = (double2*)scr;
    float2* icg = (float2*)(scr + 262144);

    hipLaunchKernelGGL(init_kernel, dim3((WIN + 255) / 256), dim3(256), 0, stream,
                       inputs, icg);
    for (int k = 0; k < NSWEEP - 1; ++k) {
        hipLaunchKernelGGL(sweep_kernel, dim3(WIN), dim3(64), 0, stream,
                           inputs, lday, W1, b1, W2, b2, W3, b3, traj, icg, E);
        hipLaunchKernelGGL(correct_kernel, dim3(1), dim3(128), 0, stream,
                           inputs, E, icg);
    }
    // final sweep: trajectory becomes self-consistent with corrected ICs
    hipLaunchKernelGGL(sweep_kernel, dim3(WIN), dim3(64), 0, stream,
                       inputs, lday, W1, b1, W2, b2, W3, b3, traj, icg, E);
    hipLaunchKernelGGL(out_kernel, dim3((T_TOTAL + 255) / 256), dim3(256), 0, stream,
                       inputs, traj, W1, b1, W2, b2, W3, b3, out);
}

// Round 16
// 1961.089 us; speedup vs baseline: 1.2880x; 1.0374x over previous
//
#include <hip/hip_runtime.h>
#include <math.h>

#define T_TOTAL 262144
#define HID 32
#define WIN 3072                      /* windows: 85-86 serial steps each */
/* window geometry: first 1024 windows have 86 steps, rest 85.
   S(w) = 85*w + min(w,1024); contiguous, covers [0, 262144). */
#define NSWEEP 5                      /* total sweeps; NSWEEP-1 corrections */
#define CH 1024                       /* correction chunk size (3 chunks) */
#define FD_EPS0 4.0                   /* FD perturbation on s0 (snow) */
#define FD_EPS1 8.0                   /* FD perturbation on s1 (water), quad 2 */
#define FD_EPS1B 4.0                  /* FD perturbation on s1, quad 3 (Richardson) */
#define LOG2E 1.4426950408889634f
#define TANH2C 2.8853900817779268f    /* 2*log2e */
#define NEG10LOG2E (-14.426950408889634f)
#define POS10LOG2E (14.426950408889634f)

#define PIN(x) asm volatile("" : "+v"(x))

typedef _Float16 f16x8 __attribute__((ext_vector_type(8)));
typedef float f32x4 __attribute__((ext_vector_type(4)));

__device__ __forceinline__ float fexp2(float x) { return __builtin_amdgcn_exp2f(x); }
__device__ __forceinline__ float frcp(float x)  { return __builtin_amdgcn_rcpf(x); }
__device__ __forceinline__ float fast_sig10(float x) {
    return frcp(1.0f + fexp2(x * NEG10LOG2E));
}
__device__ __forceinline__ float fast_tanh_clamp(float x) { // out_kernel only
    float xc = __builtin_amdgcn_fmed3f(x, -9.0f, 9.0f);
    float u  = fexp2(xc * TANH2C);
    return fmaf(-2.0f, frcp(u + 1.0f), 1.0f);
}
__device__ __forceinline__ float fast_tanh_nc(float x) {
    float u = fexp2(x * TANH2C);
    return fmaf(-2.0f, frcp(u + 1.0f), 1.0f);
}

// ---- DPP / lane helpers ----------------------------------------------------
template <int CTRL>
__device__ __forceinline__ float dpp_add(float v) {
    int t = __builtin_amdgcn_update_dpp(0, __float_as_int(v), CTRL, 0xF, 0xF, true);
    return v + __int_as_float(t);
}
__device__ __forceinline__ float allsum16(float x) {
    x = dpp_add<0xB1>(x);   // quad_perm xor1
    x = dpp_add<0x4E>(x);   // quad_perm xor2
    x = dpp_add<0x141>(x);  // row_half_mirror
    x = dpp_add<0x140>(x);  // row_mirror
    return x;
}
__device__ __forceinline__ int dpp_xor1_i(int v) {
    return __builtin_amdgcn_update_dpp(0, v, 0xB1, 0xF, 0xF, true);
}
__device__ __forceinline__ float rl(float x, int lane) {
    return __int_as_float(__builtin_amdgcn_readlane(__float_as_int(x), lane));
}
__device__ __forceinline__ float bpf(int addr, float x) {
    return __int_as_float(__builtin_amdgcn_ds_bpermute(addr, __float_as_int(x)));
}

// ---------------------------------------------------------------------------
// init: all window ICs = global Y0 guess (f32)
// ---------------------------------------------------------------------------
__global__ void init_kernel(const float* __restrict__ inputs, float2* icg) {
    int w = blockIdx.x * blockDim.x + threadIdx.x;
    if (w < WIN) icg[w] = make_float2(inputs[0], inputs[1]);
}

// ---------------------------------------------------------------------------
// Newton-Parareal sweep, FOUR REAL trajectories per wave:
//   quad 0 = unperturbed, quad 1 = +FD_EPS0 on s0,
//   quad 2 = +FD_EPS1 (8) on s1, quad 3 = +FD_EPS1B (4) on s1 (Richardson).
// R15: the C and D secondary h1 paths are MERGED into one stream selected
// by half (s0s = half ? s0D : s0C). Consumption analysis: C packed words
// are read only by row-class-2 gathers (+4 -> odd half-0 lanes), D words
// only by row-class-3 (+132 -> odd half-1 lanes), and the dpp_xor1 pair
// exchange never crosses the half boundary (lane^1 flips bit 0; half is
// bit 5) — so every consumed lane sees a BIT-IDENTICAL value to R14's
// dual-path version, at ~40 fewer VALU ops/step (the R14 regression).
// Unperturbed path unchanged from R9-R14 (validated at bf16 floor).
// Non-uniform windows: LEN = 86 for wnd<1024 else 85.
// ---------------------------------------------------------------------------
__global__ __launch_bounds__(64, 1) void sweep_kernel(
    const float* __restrict__ inputs,   // (T,5)
    const float* __restrict__ lday,     // (T,)
    const float* __restrict__ W1, const float* __restrict__ b1,
    const float* __restrict__ W2, const float* __restrict__ b2,
    const float* __restrict__ W3, const float* __restrict__ b3,
    float* __restrict__ traj,           // (T,2)
    const float2* __restrict__ icg,     // window ICs (read, f32)
    double2* __restrict__ E)            // end states (write), 4*WIN
{
    const int lane = threadIdx.x;
    const int col  = lane & 15;
    const int quad = lane >> 4;
    const int j32  = lane & 31;
    const int half = lane >> 5;
    const bool odd = (lane & 1) != 0;

    const int wnd  = blockIdx.x;
    const int S    = wnd * 85 + ((wnd < 1024) ? wnd : 1024);
    const int LEN  = (wnd < 1024) ? 86 : 85;
    const int endStep = (S + LEN < T_TOTAL - 1) ? (S + LEN) : (T_TOTAL - 1);

    // layer-1 weights, pre-scaled by 2log2e
    float w1c0 = W1[0 * HID + j32] * TANH2C, w1c1 = W1[1 * HID + j32] * TANH2C;
    float w1c2 = W1[2 * HID + j32] * TANH2C, w1c3 = W1[3 * HID + j32] * TANH2C;
    float b1j = b1[j32] * TANH2C;
    PIN(w1c0); PIN(w1c1); PIN(w1c2); PIN(w1c3); PIN(b1j);

    // W2*2log2e as f16 hi/lo B-fragments
    f16x8 Bhi0, Blo0, Bhi1, Blo1;
#pragma unroll
    for (int jj = 0; jj < 8; ++jj) {
        float w0 = W2[(quad * 8 + jj) * HID + col] * TANH2C;
        float w1v = W2[(quad * 8 + jj) * HID + col + 16] * TANH2C;
        _Float16 h0 = (_Float16)w0, h1v = (_Float16)w1v;
        Bhi0[jj] = h0;  Blo0[jj] = (_Float16)(w0 - (float)h0);
        Bhi1[jj] = h1v; Blo1[jj] = (_Float16)(w1v - (float)h1v);
    }
    PIN(Bhi0); PIN(Blo0); PIN(Bhi1); PIN(Blo1);

    float b2a2 = b2[col] * TANH2C, b2b2 = b2[col + 16] * TANH2C;
    f32x4 cb0 = {b2a2, b2a2, b2a2, b2a2};
    f32x4 cb1 = {b2b2, b2b2, b2b2, b2b2};
    PIN(cb0); PIN(cb1);

    // layer-3 weights: 5 channels per 16-lane quad
    float wca[5], wcb[5];
#pragma unroll
    for (int c = 0; c < 5; ++c) {
        wca[c] = W3[col * 5 + c] * LOG2E;
        wcb[c] = W3[(col + 16) * 5 + c] * LOG2E;
        PIN(wca[c]); PIN(wcb[c]);
    }

    float m0 = (col == 0) ? 1.f : 0.f;
    float m1 = (col == 1) ? 1.f : 0.f;
    float m2 = (col == 2) ? 1.f : 0.f;
    float m3 = (col == 3) ? 1.f : 0.f;
    float m4 = (col == 4) ? 1.f : 0.f;
    float m5 = (col == 5) ? 1.f : 0.f;
    float m6 = (col == 6) ? 1.f : 0.f;
    float m7 = (col == 7) ? 1.f : 0.f;
    float m8 = (col == 8) ? 1.f : 0.f;
    float sig1m = (col >= 5 && col <= 8) ? 1.f : 0.f;
    float zb = b3[(col < 5) ? col : 0];
    float zconst = (col < 5) ? zb * LOG2E : 0.f;
    PIN(m0); PIN(m1); PIN(m2); PIN(m3); PIN(m4); PIN(m5); PIN(m6); PIN(m7); PIN(m8);
    PIN(sig1m); PIN(zconst);

    int psel = (lane & 1) ? 0x01000504 : 0x05040100;
    // A-build gather base by row class r&3: {A,B,C,D} -> {+0,+128,+4,+132}
    int l3 = lane & 3;
    int roff = (l3 == 1) ? 128 : (l3 == 2) ? 4 : (l3 == 3) ? 132 : 0;
    int bbase = 32 * quad + roff;
    int bp0 = bbase, bp1 = bbase + 8, bp2 = bbase + 16, bp3 = bbase + 24;
    PIN(psel); PIN(bp0); PIN(bp1); PIN(bp2); PIN(bp3);

    // per-quad output-gather addresses (bytes)
    int qb = 64 * quad;
    int a_sh0 = qb + 0,  a_sh1 = qb + 4,  a_sh2 = qb + 8;
    int a_e3  = qb + 12, a_e4  = qb + 16, a_sg0 = qb + 20, a_sg1 = qb + 24;
    PIN(a_sh0); PIN(a_sh1); PIN(a_sh2); PIN(a_e3); PIN(a_e4); PIN(a_sg0); PIN(a_sg1);

    float2 ic = icg[wnd];
    double y0 = (double)ic.x + ((quad == 1) ? FD_EPS0 : 0.0);
    double y1 = (double)ic.y +
                ((quad == 2) ? FD_EPS1 : (quad == 3) ? FD_EPS1B : 0.0);
    float2* traj2 = (float2*)traj;
    if (lane == 0 && wnd == 0)
        traj2[0] = make_float2(ic.x, ic.y);

    auto rhs = [&](float s0q, float s1q, float base, float stm, float ld, float zoffk,
                   float& d0, float& d1, float& rout) {
        // broadcast the four trajectory states for layer-1
        float s0A = rl(s0q, 0),  s1A = rl(s1q, 0);
        float s0B = rl(s0q, 16), s1B = rl(s1q, 16);
        float s0C = rl(s0q, 32), s1C = rl(s1q, 32);
        float s0D = rl(s0q, 48), s1D = rl(s1q, 48);
        float s0p = half ? s0B : s0A;
        float s1p = half ? s1B : s1A;
        float s0s = half ? s0D : s0C;       // merged secondary: C half0, D half1
        float s1s = half ? s1D : s1C;
        // layer-1: primary and merged-secondary paths
        float prep = fmaf(s1p, w1c1, fmaf(s0p, w1c0, base));
        float pres = fmaf(s1s, w1c1, fmaf(s0s, w1c0, base));
        float up_ = fexp2(prep);
        float us_ = fexp2(pres);
        float h1p = fmaf(-2.0f, frcp(up_ + 1.0f), 1.0f);
        float h1s = fmaf(-2.0f, frcp(us_ + 1.0f), 1.0f);
        union { _Float16 h; unsigned short u; } cvp, cvs;
        cvp.h = (_Float16)h1p; cvs.h = (_Float16)h1s;
        int ownp = (int)cvp.u, owns = (int)cvs.u;
        int nbp = dpp_xor1_i(ownp), nbs = dpp_xor1_i(owns);
        int pkp = __builtin_amdgcn_perm(nbp, ownp, psel);
        int pks = __builtin_amdgcn_perm(nbs, owns, psel);
        // packed words: A=even half0, B=even half1, C=odd half0, D=odd half1
        int pk  = odd ? pks : pkp;
        int g0i = __builtin_amdgcn_ds_bpermute(bp0, pk);
        int g1i = __builtin_amdgcn_ds_bpermute(bp1, pk);
        int g2i = __builtin_amdgcn_ds_bpermute(bp2, pk);
        int g3i = __builtin_amdgcn_ds_bpermute(bp3, pk);
        union { int i[4]; f16x8 h; } au;
        au.i[0] = g0i; au.i[1] = g1i; au.i[2] = g2i; au.i[3] = g3i;
        f16x8 A = au.h;
        f32x4 zz = {0.f, 0.f, 0.f, 0.f};
        f32x4 chi0 = __builtin_amdgcn_mfma_f32_16x16x32_f16(A, Bhi0, cb0, 0, 0, 0);
        f32x4 clo0 = __builtin_amdgcn_mfma_f32_16x16x32_f16(A, Blo0, zz, 0, 0, 0);
        f32x4 chi1 = __builtin_amdgcn_mfma_f32_16x16x32_f16(A, Bhi1, cb1, 0, 0, 0);
        f32x4 clo1 = __builtin_amdgcn_mfma_f32_16x16x32_f16(A, Blo1, zz, 0, 0, 0);
        // per-quad trajectory row select (C rows: 4q+0=A, +1=B, +2=C, +3=D)
        float tA0 = chi0[0] + clo0[0], tB0 = chi0[1] + clo0[1];
        float tC0 = chi0[2] + clo0[2], tD0 = chi0[3] + clo0[3];
        float tA1 = chi1[0] + clo1[0], tB1 = chi1[1] + clo1[1];
        float tC1 = chi1[2] + clo1[2], tD1 = chi1[3] + clo1[3];
        float t0 = (quad == 0) ? tA0 : (quad == 1) ? tB0 : (quad == 2) ? tC0 : tD0;
        float t1 = (quad == 0) ? tA1 : (quad == 1) ? tB1 : (quad == 2) ? tC1 : tD1;
        float ua = fexp2(t0);
        float ub = fexp2(t1);
        float g0 = fmaf(-2.0f, frcp(ua + 1.0f), 1.0f);
        float g1 = fmaf(-2.0f, frcp(ub + 1.0f), 1.0f);
        float r0 = fmaf(g0, wca[0], g1 * wcb[0]);
        float r1 = fmaf(g0, wca[1], g1 * wcb[1]);
        float r2 = fmaf(g0, wca[2], g1 * wcb[2]);
        float r3 = fmaf(g0, wca[3], g1 * wcb[3]);
        float r4 = fmaf(g0, wca[4], g1 * wcb[4]);
        float s0r = allsum16(r0);
        float s1r = allsum16(r1);
        float s2r = allsum16(r2);
        float s3r = allsum16(r3);
        float s4r = allsum16(r4);
        float zs0 = s0q * NEG10LOG2E;           // own quad's trajectory
        float zs1 = s1q * NEG10LOG2E;
        float zoff = fmaf(zs0, m5, fmaf(zs1, m6, zoffk));
        float zarg = fmaf(s0r, m0, fmaf(s1r, m1, fmaf(s2r, m2,
                     fmaf(s3r, m3, fmaf(s4r, m4, zoff)))));
        float u = fexp2(zarg);
        float r = frcp(u + sig1m);
        float w = fmaf(0.5f, u, -0.5f * r);
        float sh0 = bpf(a_sh0, w), sh1 = bpf(a_sh1, w), sh2 = bpf(a_sh2, w);
        float e3  = bpf(a_e3, u),  e4  = bpf(a_e4, u);
        float sg0 = bpf(a_sg0, r), sg1 = bpf(a_sg1, r);
        float p_snow = fmaxf(sh0 * stm, 0.f);
        float p_rain = fmaxf(sh1, 0.f);
        float melt   = fmaxf(sg0 * sh2, 0.f);
        float etq    = sg1 * fmaf(e3, ld, e4);
        d0 = p_snow - melt;
        d1 = (p_rain + melt) - etq;
        rout = r;
    };

    float pA = inputs[S * 5 + 2],       tmA = inputs[S * 5 + 3],       ldA = lday[S];
    float pB = inputs[(S + 1) * 5 + 2], tmB = inputs[(S + 1) * 5 + 3], ldB = lday[S + 1];
    float pC = inputs[(S + 2) * 5 + 2], tmC = inputs[(S + 2) * 5 + 3], ldC = lday[S + 2];
    float stmA = fast_sig10(-tmA);
    float stmB = fast_sig10(-tmB);
    float stmm = fast_sig10(-0.5f * (tmA + tmB));
    float baseA = fmaf(pA, w1c2, fmaf(tmA, w1c3, b1j));
    float baseB = fmaf(pB, w1c2, fmaf(tmB, w1c3, b1j));

    for (int n = S; n < endStep; ++n) {
        const float ldm = 0.5f * (ldA + ldB);
        const float pm  = 0.5f * (pA + pB);
        const float tmm = 0.5f * (tmA + tmB);
        const float basem = fmaf(pm, w1c2, fmaf(tmm, w1c3, b1j));
        const float ztm_m = (0.5f * (tmB + tmC)) * POS10LOG2E;
        const float ztm_b = tmC * POS10LOG2E;
        const float zoffk = fmaf(ztm_m, m7, fmaf(ztm_b, m8, zconst));

        const float fy0 = (float)y0, fy1 = (float)y1;
        float k10, k11, k20, k21, k30, k31, k40, k41, rd;
        rhs(fy0,                  fy1,                  baseA, stmA, ldA, zoffk, k10, k11, rd);
        rhs(fmaf(0.5f, k10, fy0), fmaf(0.5f, k11, fy1), basem, stmm, ldm, zoffk, k20, k21, rd);
        rhs(fmaf(0.5f, k20, fy0), fmaf(0.5f, k21, fy1), basem, stmm, ldm, zoffk, k30, k31, rd);
        rhs(fy0 + k30,            fy1 + k31,            baseB, stmB, ldB, zoffk, k40, k41, rd);
        const float stmm_n = rl(rd, 7);
        const float stmB_n = rl(rd, 8);

        const float s0sum = (k10 + 2.0f * k20) + (2.0f * k30 + k40);
        const float s1sum = (k11 + 2.0f * k21) + (2.0f * k31 + k41);
        y0 += (1.0 / 6.0) * (double)s0sum;
        y1 += (1.0 / 6.0) * (double)s1sum;

        if (lane == 0)
            traj2[n + 1] = make_float2((float)y0, (float)y1);

        stmA = stmB; stmB = stmB_n; stmm = stmm_n;
        baseA = baseB;
        baseB = fmaf(pC, w1c2, fmaf(tmC, w1c3, b1j));
        pA = pB; tmA = tmB; ldA = ldB;
        pB = pC; tmB = tmC; ldB = ldC;
        const int np3 = (n + 3 < T_TOTAL) ? (n + 3) : (T_TOTAL - 1);
        pC = inputs[np3 * 5 + 2]; tmC = inputs[np3 * 5 + 3]; ldC = lday[np3];
    }

    if (lane == 0)  E[wnd]           = make_double2(y0, y1);  // unperturbed
    if (lane == 16) E[WIN + wnd]     = make_double2(y0, y1);  // +eps0 on s0
    if (lane == 32) E[2 * WIN + wnd] = make_double2(y0, y1);  // +8 on s1
    if (lane == 48) E[3 * WIN + wnd] = make_double2(y0, y1);  // +4 on s1
}

// ---------------------------------------------------------------------------
// Sequential Newton-Parareal correction — chunked double-buffered LDS,
// TWO WAVES (128 threads), serial loop UNROLLED x8 (R13-validated: ~64 us).
// J11 by Richardson extrapolation, J11 = 2*S(4) - S(8) (R14-validated:
// 4 corrections reach the bf16 floor). Clamps wide-open (R6). J01 := 0.
// ---------------------------------------------------------------------------
__global__ __launch_bounds__(128) void correct_kernel(
    const float* __restrict__ inputs,
    const double2* __restrict__ E,
    float2* __restrict__ icg) {
    __shared__ float sJ00[2][CH], sJ10[2][CH], sJ11[2][CH];
    __shared__ float sE0x[2][CH], sE0y[2][CH];
    __shared__ float sGx[2][CH],  sGy[2][CH];     // 2*7*1024*4 = 57344 B
    const int tid = threadIdx.x;

    auto stage_one = [&](int buf, int i, int w) {
        double2 e0 = E[w];
        double2 e1 = E[WIN + w];
        double2 e2 = E[2 * WIN + w];
        double2 e3 = E[3 * WIN + w];
        float2 g   = icg[w];
        float J00 = (float)((e1.x - e0.x) * (1.0 / FD_EPS0));
        float J10 = (float)((e1.y - e0.y) * (1.0 / FD_EPS0));
        // Richardson: 2*(E(+4)-E0)/4 - (E(+8)-E0)/8
        float J11 = (float)((e3.y - e0.y) * (2.0 / FD_EPS1B)
                          - (e2.y - e0.y) * (1.0 / FD_EPS1));
        sJ00[buf][i] = fminf(fmaxf(J00, -0.15f), 1.15f);   // wide-open (R6)
        sJ10[buf][i] = fminf(fmaxf(J10, -0.30f), 1.80f);
        sJ11[buf][i] = fminf(fmaxf(J11,  0.00f), 1.10f);
        sE0x[buf][i] = (float)e0.x; sE0y[buf][i] = (float)e0.y;
        sGx[buf][i]  = g.x;         sGy[buf][i]  = g.y;
    };

    // prologue: all 128 threads stage chunk 0 into buffer 0
    for (int i = tid; i < CH; i += 128) stage_one(0, i, i);
    __syncthreads();

    float y0c = inputs[0];
    float y1c = inputs[1];
    for (int c = 0; c < 3; ++c) {
        const int buf = c & 1;
        if (tid == 0) {
            // wave 0: serial recurrence over chunk c — LDS reads +
            // fire-and-forget global stores only; unroll 8 batches the
            // LDS reads ahead of the f32 chain (R8/R13 recipe).
            const int wbase = c * CH;
#pragma unroll 8
            for (int i = 0; i < CH; ++i) {
                float d0 = y0c - sGx[buf][i];
                float d1 = y1c - sGy[buf][i];
                d0 = fminf(fmaxf(d0, -50.0f), 50.0f);      // trust region
                d1 = fminf(fmaxf(d1, -400.0f), 400.0f);
                icg[wbase + i] = make_float2(y0c, y1c);    // fire-and-forget
                y0c = fmaf(sJ00[buf][i], d0, sE0x[buf][i]);        // J01 = 0
                y1c = fmaf(sJ10[buf][i], d0, fmaf(sJ11[buf][i], d1, sE0y[buf][i]));
                y0c = fminf(fmaxf(y0c, -5.0f), 1000.0f);   // physical sanity
                y1c = fminf(fmaxf(y1c, -5.0f), 5000.0f);
            }
        } else if (tid >= 64 && c + 1 < 3) {
            // wave 1: stage chunk c+1 into the other buffer, truly overlapped
            for (int i = tid - 64; i < CH; i += 64)
                stage_one((c + 1) & 1, i, (c + 1) * CH + i);
        }
        __syncthreads();
    }
}

// ---------------------------------------------------------------------------
// Parallel readout: out[t] = mlp(relu(state), p, tm)[4]
// ---------------------------------------------------------------------------
__global__ __launch_bounds__(256) void out_kernel(
    const float* __restrict__ inputs,
    const float* __restrict__ traj,
    const float* __restrict__ W1, const float* __restrict__ b1,
    const float* __restrict__ W2, const float* __restrict__ b2,
    const float* __restrict__ W3, const float* __restrict__ b3,
    float* __restrict__ out)
{
    __shared__ float sW1[4 * HID];
    __shared__ float sb1[HID];
    __shared__ float sW2T[HID * HID];
    __shared__ float sb2[HID];
    __shared__ float sw3[HID];
    for (int i = threadIdx.x; i < 4 * HID; i += 256) sW1[i] = W1[i];
    for (int i = threadIdx.x; i < HID; i += 256) {
        sb1[i] = b1[i]; sb2[i] = b2[i]; sw3[i] = W3[i * 5 + 4];
    }
    for (int idx = threadIdx.x; idx < HID * HID; idx += 256) {
        int jj = idx >> 5, ii = idx & 31;
        sW2T[idx] = W2[ii * HID + jj];
    }
    __syncthreads();

    int t = blockIdx.x * 256 + threadIdx.x;
    if (t >= T_TOTAL) return;

    float2 st = ((const float2*)traj)[t];
    float s0 = fmaxf(st.x, 0.0f);
    float s1 = fmaxf(st.y, 0.0f);
    float p  = inputs[t * 5 + 2];
    float tm = inputs[t * 5 + 3];

    float h1[HID];
#pragma unroll
    for (int jj = 0; jj < HID; ++jj) {
        float pre = fmaf(s0, sW1[jj], fmaf(s1, sW1[HID + jj],
                    fmaf(p, sW1[2 * HID + jj],
                    fmaf(tm, sW1[3 * HID + jj], sb1[jj]))));
        h1[jj] = fast_tanh_clamp(pre);
    }
    float o = b3[4];
#pragma unroll 4
    for (int jj = 0; jj < HID; ++jj) {
        float a0 = sb2[jj], a1 = 0.f, a2 = 0.f, a3 = 0.f;
#pragma unroll
        for (int ii = 0; ii < HID; ii += 4) {
            a0 = fmaf(h1[ii + 0], sW2T[jj * HID + ii + 0], a0);
            a1 = fmaf(h1[ii + 1], sW2T[jj * HID + ii + 1], a1);
            a2 = fmaf(h1[ii + 2], sW2T[jj * HID + ii + 2], a2);
            a3 = fmaf(h1[ii + 3], sW2T[jj * HID + ii + 3], a3);
        }
        o = fmaf(fast_tanh_nc((a0 + a1) + (a2 + a3)), sw3[jj], o);
    }
    out[t] = o;
}

extern "C" void kernel_launch(void* const* d_in, const int* in_sizes, int n_in,
                              void* d_out, int out_size, void* d_ws, size_t ws_size,
                              hipStream_t stream) {
    (void)in_sizes; (void)n_in; (void)out_size; (void)ws_size;
    const float* inputs = (const float*)d_in[0];
    const float* lday   = (const float*)d_in[1];
    const float* W1     = (const float*)d_in[2];
    const float* b1     = (const float*)d_in[3];
    const float* W2     = (const float*)d_in[4];
    const float* b2     = (const float*)d_in[5];
    const float* W3     = (const float*)d_in[6];
    const float* b3     = (const float*)d_in[7];
    float* out  = (float*)d_out;
    float* traj = (float*)d_ws;                 // T*2 floats = 2 MB

    // small Parareal arrays live in d_out (scratch until out_kernel, 1 MB)
    // E = 4*WIN double2 = 196608 B at offset 0; icg = WIN float2 = 24576 B
    // at offset 262144. Total 286720 <= 1 MB.
    char* scr = (char*)d_out;
    double2* E  = (double2*)scr;
    float2* icg = (float2*)(scr + 262144);

    hipLaunchKernelGGL(init_kernel, dim3((WIN + 255) / 256), dim3(256), 0, stream,
                       inputs, icg);
    for (int k = 0; k < NSWEEP - 1; ++k) {
        hipLaunchKernelGGL(sweep_kernel, dim3(WIN), dim3(64), 0, stream,
                           inputs, lday, W1, b1, W2, b2, W3, b3, traj, icg, E);
        hipLaunchKernelGGL(correct_kernel, dim3(1), dim3(128), 0, stream,
                           inputs, E, icg);
    }
    // final sweep: trajectory becomes self-consistent with corrected ICs
    hipLaunchKernelGGL(sweep_kernel, dim3(WIN), dim3(64), 0, stream,
                       inputs, lday, W1, b1, W2, b2, W3, b3, traj, icg, E);
    hipLaunchKernelGGL(out_kernel, dim3((T_TOTAL + 255) / 256), dim3(256), 0, stream,
                       inputs, traj, W1, b1, W2, b2, W3, b3, out);
}

// Round 18
// 1960.415 us; speedup vs baseline: 1.2884x; 1.0003x over previous
//
#include <hip/hip_runtime.h>
#include <math.h>

#define T_TOTAL 262144
#define HID 32
#define WIN 3072                      /* windows: 85-86 serial steps each */
/* window geometry: first 1024 windows have 86 steps, rest 85.
   S(w) = 85*w + min(w,1024); contiguous, covers [0, 262144). */
#define NSWEEP 5                      /* total sweeps; NSWEEP-1 corrections */
#define CH 1024                       /* correction chunk size (3 chunks) */
#define FD_EPS0 4.0                   /* FD perturbation on s0 (snow) */
#define FD_EPS1 8.0                   /* FD perturbation on s1 (water), quad 2 */
#define FD_EPS1B 4.0                  /* FD perturbation on s1, quad 3 (Richardson) */
#define LOG2E 1.4426950408889634f
#define TANH2C 2.8853900817779268f    /* 2*log2e */
#define NEG10LOG2E (-14.426950408889634f)
#define POS10LOG2E (14.426950408889634f)

#define PIN(x) asm volatile("" : "+v"(x))

typedef _Float16 f16x8 __attribute__((ext_vector_type(8)));
typedef float f32x4 __attribute__((ext_vector_type(4)));

__device__ __forceinline__ float fexp2(float x) { return __builtin_amdgcn_exp2f(x); }
__device__ __forceinline__ float frcp(float x)  { return __builtin_amdgcn_rcpf(x); }
__device__ __forceinline__ float fast_sig10(float x) {
    return frcp(1.0f + fexp2(x * NEG10LOG2E));
}
__device__ __forceinline__ float fast_tanh_clamp(float x) { // out_kernel only
    float xc = __builtin_amdgcn_fmed3f(x, -9.0f, 9.0f);
    float u  = fexp2(xc * TANH2C);
    return fmaf(-2.0f, frcp(u + 1.0f), 1.0f);
}
__device__ __forceinline__ float fast_tanh_nc(float x) {
    float u = fexp2(x * TANH2C);
    return fmaf(-2.0f, frcp(u + 1.0f), 1.0f);
}

// ---- DPP / lane helpers ----------------------------------------------------
template <int CTRL>
__device__ __forceinline__ float dpp_add(float v) {
    int t = __builtin_amdgcn_update_dpp(0, __float_as_int(v), CTRL, 0xF, 0xF, true);
    return v + __int_as_float(t);
}
__device__ __forceinline__ float allsum16(float x) {
    x = dpp_add<0xB1>(x);   // quad_perm xor1
    x = dpp_add<0x4E>(x);   // quad_perm xor2
    x = dpp_add<0x141>(x);  // row_half_mirror
    x = dpp_add<0x140>(x);  // row_mirror
    return x;
}
__device__ __forceinline__ int dpp_xor1_i(int v) {
    return __builtin_amdgcn_update_dpp(0, v, 0xB1, 0xF, 0xF, true);
}
__device__ __forceinline__ float rl(float x, int lane) {
    return __int_as_float(__builtin_amdgcn_readlane(__float_as_int(x), lane));
}
__device__ __forceinline__ float bpf(int addr, float x) {
    return __int_as_float(__builtin_amdgcn_ds_bpermute(addr, __float_as_int(x)));
}

// ---------------------------------------------------------------------------
// init: all window ICs = global Y0 guess (f32)
// ---------------------------------------------------------------------------
__global__ void init_kernel(const float* __restrict__ inputs, float2* icg) {
    int w = blockIdx.x * blockDim.x + threadIdx.x;
    if (w < WIN) icg[w] = make_float2(inputs[0], inputs[1]);
}

// ---------------------------------------------------------------------------
// Newton-Parareal sweep, FOUR REAL trajectories per wave:
//   quad 0 = unperturbed, quad 1 = +FD_EPS0 on s0,
//   quad 2 = +FD_EPS1 (8) on s1, quad 3 = +FD_EPS1B (4) on s1 (Richardson).
// R15/R16: merged C/D secondary h1 stream selected by half — bit-identical
// to the dual-path version on every consumed lane (validated R16, absmax
// at bf16 floor, sweep 335 us @ 3 waves/SIMD, VALUBusy 86.6%).
// R17 calibrated the correction contraction: 3 corrections -> absmax 0.051
// (fail), 4 corrections -> bf16 floor. NSWEEP=5 is the convergence minimum.
// Non-uniform windows: LEN = 86 for wnd<1024 else 85.
// ---------------------------------------------------------------------------
__global__ __launch_bounds__(64, 1) void sweep_kernel(
    const float* __restrict__ inputs,   // (T,5)
    const float* __restrict__ lday,     // (T,)
    const float* __restrict__ W1, const float* __restrict__ b1,
    const float* __restrict__ W2, const float* __restrict__ b2,
    const float* __restrict__ W3, const float* __restrict__ b3,
    float* __restrict__ traj,           // (T,2)
    const float2* __restrict__ icg,     // window ICs (read, f32)
    double2* __restrict__ E)            // end states (write), 4*WIN
{
    const int lane = threadIdx.x;
    const int col  = lane & 15;
    const int quad = lane >> 4;
    const int j32  = lane & 31;
    const int half = lane >> 5;
    const bool odd = (lane & 1) != 0;

    const int wnd  = blockIdx.x;
    const int S    = wnd * 85 + ((wnd < 1024) ? wnd : 1024);
    const int LEN  = (wnd < 1024) ? 86 : 85;
    const int endStep = (S + LEN < T_TOTAL - 1) ? (S + LEN) : (T_TOTAL - 1);

    // layer-1 weights, pre-scaled by 2log2e
    float w1c0 = W1[0 * HID + j32] * TANH2C, w1c1 = W1[1 * HID + j32] * TANH2C;
    float w1c2 = W1[2 * HID + j32] * TANH2C, w1c3 = W1[3 * HID + j32] * TANH2C;
    float b1j = b1[j32] * TANH2C;
    PIN(w1c0); PIN(w1c1); PIN(w1c2); PIN(w1c3); PIN(b1j);

    // W2*2log2e as f16 hi/lo B-fragments
    f16x8 Bhi0, Blo0, Bhi1, Blo1;
#pragma unroll
    for (int jj = 0; jj < 8; ++jj) {
        float w0 = W2[(quad * 8 + jj) * HID + col] * TANH2C;
        float w1v = W2[(quad * 8 + jj) * HID + col + 16] * TANH2C;
        _Float16 h0 = (_Float16)w0, h1v = (_Float16)w1v;
        Bhi0[jj] = h0;  Blo0[jj] = (_Float16)(w0 - (float)h0);
        Bhi1[jj] = h1v; Blo1[jj] = (_Float16)(w1v - (float)h1v);
    }
    PIN(Bhi0); PIN(Blo0); PIN(Bhi1); PIN(Blo1);

    float b2a2 = b2[col] * TANH2C, b2b2 = b2[col + 16] * TANH2C;
    f32x4 cb0 = {b2a2, b2a2, b2a2, b2a2};
    f32x4 cb1 = {b2b2, b2b2, b2b2, b2b2};
    PIN(cb0); PIN(cb1);

    // layer-3 weights: 5 channels per 16-lane quad
    float wca[5], wcb[5];
#pragma unroll
    for (int c = 0; c < 5; ++c) {
        wca[c] = W3[col * 5 + c] * LOG2E;
        wcb[c] = W3[(col + 16) * 5 + c] * LOG2E;
        PIN(wca[c]); PIN(wcb[c]);
    }

    float m0 = (col == 0) ? 1.f : 0.f;
    float m1 = (col == 1) ? 1.f : 0.f;
    float m2 = (col == 2) ? 1.f : 0.f;
    float m3 = (col == 3) ? 1.f : 0.f;
    float m4 = (col == 4) ? 1.f : 0.f;
    float m5 = (col == 5) ? 1.f : 0.f;
    float m6 = (col == 6) ? 1.f : 0.f;
    float m7 = (col == 7) ? 1.f : 0.f;
    float m8 = (col == 8) ? 1.f : 0.f;
    float sig1m = (col >= 5 && col <= 8) ? 1.f : 0.f;
    float zb = b3[(col < 5) ? col : 0];
    float zconst = (col < 5) ? zb * LOG2E : 0.f;
    PIN(m0); PIN(m1); PIN(m2); PIN(m3); PIN(m4); PIN(m5); PIN(m6); PIN(m7); PIN(m8);
    PIN(sig1m); PIN(zconst);

    int psel = (lane & 1) ? 0x01000504 : 0x05040100;
    // A-build gather base by row class r&3: {A,B,C,D} -> {+0,+128,+4,+132}
    int l3 = lane & 3;
    int roff = (l3 == 1) ? 128 : (l3 == 2) ? 4 : (l3 == 3) ? 132 : 0;
    int bbase = 32 * quad + roff;
    int bp0 = bbase, bp1 = bbase + 8, bp2 = bbase + 16, bp3 = bbase + 24;
    PIN(psel); PIN(bp0); PIN(bp1); PIN(bp2); PIN(bp3);

    // per-quad output-gather addresses (bytes)
    int qb = 64 * quad;
    int a_sh0 = qb + 0,  a_sh1 = qb + 4,  a_sh2 = qb + 8;
    int a_e3  = qb + 12, a_e4  = qb + 16, a_sg0 = qb + 20, a_sg1 = qb + 24;
    PIN(a_sh0); PIN(a_sh1); PIN(a_sh2); PIN(a_e3); PIN(a_e4); PIN(a_sg0); PIN(a_sg1);

    float2 ic = icg[wnd];
    double y0 = (double)ic.x + ((quad == 1) ? FD_EPS0 : 0.0);
    double y1 = (double)ic.y +
                ((quad == 2) ? FD_EPS1 : (quad == 3) ? FD_EPS1B : 0.0);
    float2* traj2 = (float2*)traj;
    if (lane == 0 && wnd == 0)
        traj2[0] = make_float2(ic.x, ic.y);

    auto rhs = [&](float s0q, float s1q, float base, float stm, float ld, float zoffk,
                   float& d0, float& d1, float& rout) {
        // broadcast the four trajectory states for layer-1
        float s0A = rl(s0q, 0),  s1A = rl(s1q, 0);
        float s0B = rl(s0q, 16), s1B = rl(s1q, 16);
        float s0C = rl(s0q, 32), s1C = rl(s1q, 32);
        float s0D = rl(s0q, 48), s1D = rl(s1q, 48);
        float s0p = half ? s0B : s0A;
        float s1p = half ? s1B : s1A;
        float s0s = half ? s0D : s0C;       // merged secondary: C half0, D half1
        float s1s = half ? s1D : s1C;
        // layer-1: primary and merged-secondary paths
        float prep = fmaf(s1p, w1c1, fmaf(s0p, w1c0, base));
        float pres = fmaf(s1s, w1c1, fmaf(s0s, w1c0, base));
        float up_ = fexp2(prep);
        float us_ = fexp2(pres);
        float h1p = fmaf(-2.0f, frcp(up_ + 1.0f), 1.0f);
        float h1s = fmaf(-2.0f, frcp(us_ + 1.0f), 1.0f);
        union { _Float16 h; unsigned short u; } cvp, cvs;
        cvp.h = (_Float16)h1p; cvs.h = (_Float16)h1s;
        int ownp = (int)cvp.u, owns = (int)cvs.u;
        int nbp = dpp_xor1_i(ownp), nbs = dpp_xor1_i(owns);
        int pkp = __builtin_amdgcn_perm(nbp, ownp, psel);
        int pks = __builtin_amdgcn_perm(nbs, owns, psel);
        // packed words: A=even half0, B=even half1, C=odd half0, D=odd half1
        int pk  = odd ? pks : pkp;
        int g0i = __builtin_amdgcn_ds_bpermute(bp0, pk);
        int g1i = __builtin_amdgcn_ds_bpermute(bp1, pk);
        int g2i = __builtin_amdgcn_ds_bpermute(bp2, pk);
        int g3i = __builtin_amdgcn_ds_bpermute(bp3, pk);
        union { int i[4]; f16x8 h; } au;
        au.i[0] = g0i; au.i[1] = g1i; au.i[2] = g2i; au.i[3] = g3i;
        f16x8 A = au.h;
        f32x4 zz = {0.f, 0.f, 0.f, 0.f};
        f32x4 chi0 = __builtin_amdgcn_mfma_f32_16x16x32_f16(A, Bhi0, cb0, 0, 0, 0);
        f32x4 clo0 = __builtin_amdgcn_mfma_f32_16x16x32_f16(A, Blo0, zz, 0, 0, 0);
        f32x4 chi1 = __builtin_amdgcn_mfma_f32_16x16x32_f16(A, Bhi1, cb1, 0, 0, 0);
        f32x4 clo1 = __builtin_amdgcn_mfma_f32_16x16x32_f16(A, Blo1, zz, 0, 0, 0);
        // per-quad trajectory row select (C rows: 4q+0=A, +1=B, +2=C, +3=D)
        float tA0 = chi0[0] + clo0[0], tB0 = chi0[1] + clo0[1];
        float tC0 = chi0[2] + clo0[2], tD0 = chi0[3] + clo0[3];
        float tA1 = chi1[0] + clo1[0], tB1 = chi1[1] + clo1[1];
        float tC1 = chi1[2] + clo1[2], tD1 = chi1[3] + clo1[3];
        float t0 = (quad == 0) ? tA0 : (quad == 1) ? tB0 : (quad == 2) ? tC0 : tD0;
        float t1 = (quad == 0) ? tA1 : (quad == 1) ? tB1 : (quad == 2) ? tC1 : tD1;
        float ua = fexp2(t0);
        float ub = fexp2(t1);
        float g0 = fmaf(-2.0f, frcp(ua + 1.0f), 1.0f);
        float g1 = fmaf(-2.0f, frcp(ub + 1.0f), 1.0f);
        float r0 = fmaf(g0, wca[0], g1 * wcb[0]);
        float r1 = fmaf(g0, wca[1], g1 * wcb[1]);
        float r2 = fmaf(g0, wca[2], g1 * wcb[2]);
        float r3 = fmaf(g0, wca[3], g1 * wcb[3]);
        float r4 = fmaf(g0, wca[4], g1 * wcb[4]);
        float s0r = allsum16(r0);
        float s1r = allsum16(r1);
        float s2r = allsum16(r2);
        float s3r = allsum16(r3);
        float s4r = allsum16(r4);
        float zs0 = s0q * NEG10LOG2E;           // own quad's trajectory
        float zs1 = s1q * NEG10LOG2E;
        float zoff = fmaf(zs0, m5, fmaf(zs1, m6, zoffk));
        float zarg = fmaf(s0r, m0, fmaf(s1r, m1, fmaf(s2r, m2,
                     fmaf(s3r, m3, fmaf(s4r, m4, zoff)))));
        float u = fexp2(zarg);
        float r = frcp(u + sig1m);
        float w = fmaf(0.5f, u, -0.5f * r);
        float sh0 = bpf(a_sh0, w), sh1 = bpf(a_sh1, w), sh2 = bpf(a_sh2, w);
        float e3  = bpf(a_e3, u),  e4  = bpf(a_e4, u);
        float sg0 = bpf(a_sg0, r), sg1 = bpf(a_sg1, r);
        float p_snow = fmaxf(sh0 * stm, 0.f);
        float p_rain = fmaxf(sh1, 0.f);
        float melt   = fmaxf(sg0 * sh2, 0.f);
        float etq    = sg1 * fmaf(e3, ld, e4);
        d0 = p_snow - melt;
        d1 = (p_rain + melt) - etq;
        rout = r;
    };

    float pA = inputs[S * 5 + 2],       tmA = inputs[S * 5 + 3],       ldA = lday[S];
    float pB = inputs[(S + 1) * 5 + 2], tmB = inputs[(S + 1) * 5 + 3], ldB = lday[S + 1];
    float pC = inputs[(S + 2) * 5 + 2], tmC = inputs[(S + 2) * 5 + 3], ldC = lday[S + 2];
    float stmA = fast_sig10(-tmA);
    float stmB = fast_sig10(-tmB);
    float stmm = fast_sig10(-0.5f * (tmA + tmB));
    float baseA = fmaf(pA, w1c2, fmaf(tmA, w1c3, b1j));
    float baseB = fmaf(pB, w1c2, fmaf(tmB, w1c3, b1j));

    for (int n = S; n < endStep; ++n) {
        const float ldm = 0.5f * (ldA + ldB);
        const float pm  = 0.5f * (pA + pB);
        const float tmm = 0.5f * (tmA + tmB);
        const float basem = fmaf(pm, w1c2, fmaf(tmm, w1c3, b1j));
        const float ztm_m = (0.5f * (tmB + tmC)) * POS10LOG2E;
        const float ztm_b = tmC * POS10LOG2E;
        const float zoffk = fmaf(ztm_m, m7, fmaf(ztm_b, m8, zconst));

        const float fy0 = (float)y0, fy1 = (float)y1;
        float k10, k11, k20, k21, k30, k31, k40, k41, rd;
        rhs(fy0,                  fy1,                  baseA, stmA, ldA, zoffk, k10, k11, rd);
        rhs(fmaf(0.5f, k10, fy0), fmaf(0.5f, k11, fy1), basem, stmm, ldm, zoffk, k20, k21, rd);
        rhs(fmaf(0.5f, k20, fy0), fmaf(0.5f, k21, fy1), basem, stmm, ldm, zoffk, k30, k31, rd);
        rhs(fy0 + k30,            fy1 + k31,            baseB, stmB, ldB, zoffk, k40, k41, rd);
        const float stmm_n = rl(rd, 7);
        const float stmB_n = rl(rd, 8);

        const float s0sum = (k10 + 2.0f * k20) + (2.0f * k30 + k40);
        const float s1sum = (k11 + 2.0f * k21) + (2.0f * k31 + k41);
        y0 += (1.0 / 6.0) * (double)s0sum;
        y1 += (1.0 / 6.0) * (double)s1sum;

        if (lane == 0)
            traj2[n + 1] = make_float2((float)y0, (float)y1);

        stmA = stmB; stmB = stmB_n; stmm = stmm_n;
        baseA = baseB;
        baseB = fmaf(pC, w1c2, fmaf(tmC, w1c3, b1j));
        pA = pB; tmA = tmB; ldA = ldB;
        pB = pC; tmB = tmC; ldB = ldC;
        const int np3 = (n + 3 < T_TOTAL) ? (n + 3) : (T_TOTAL - 1);
        pC = inputs[np3 * 5 + 2]; tmC = inputs[np3 * 5 + 3]; ldC = lday[np3];
    }

    if (lane == 0)  E[wnd]           = make_double2(y0, y1);  // unperturbed
    if (lane == 16) E[WIN + wnd]     = make_double2(y0, y1);  // +eps0 on s0
    if (lane == 32) E[2 * WIN + wnd] = make_double2(y0, y1);  // +8 on s1
    if (lane == 48) E[3 * WIN + wnd] = make_double2(y0, y1);  // +4 on s1
}

// ---------------------------------------------------------------------------
// Sequential Newton-Parareal correction — chunked double-buffered LDS,
// TWO WAVES (128 threads), serial loop UNROLLED x8 (R13-validated: ~64 us).
// J11 by Richardson extrapolation, J11 = 2*S(4) - S(8) (R14/R16-validated:
// 4 corrections reach the bf16 floor; R17 proved 3 do not).
// Clamps wide-open (R6). J01 := 0.
// ---------------------------------------------------------------------------
__global__ __launch_bounds__(128) void correct_kernel(
    const float* __restrict__ inputs,
    const double2* __restrict__ E,
    float2* __restrict__ icg) {
    __shared__ float sJ00[2][CH], sJ10[2][CH], sJ11[2][CH];
    __shared__ float sE0x[2][CH], sE0y[2][CH];
    __shared__ float sGx[2][CH],  sGy[2][CH];     // 2*7*1024*4 = 57344 B
    const int tid = threadIdx.x;

    auto stage_one = [&](int buf, int i, int w) {
        double2 e0 = E[w];
        double2 e1 = E[WIN + w];
        double2 e2 = E[2 * WIN + w];
        double2 e3 = E[3 * WIN + w];
        float2 g   = icg[w];
        float J00 = (float)((e1.x - e0.x) * (1.0 / FD_EPS0));
        float J10 = (float)((e1.y - e0.y) * (1.0 / FD_EPS0));
        // Richardson: 2*(E(+4)-E0)/4 - (E(+8)-E0)/8
        float J11 = (float)((e3.y - e0.y) * (2.0 / FD_EPS1B)
                          - (e2.y - e0.y) * (1.0 / FD_EPS1));
        sJ00[buf][i] = fminf(fmaxf(J00, -0.15f), 1.15f);   // wide-open (R6)
        sJ10[buf][i] = fminf(fmaxf(J10, -0.30f), 1.80f);
        sJ11[buf][i] = fminf(fmaxf(J11,  0.00f), 1.10f);
        sE0x[buf][i] = (float)e0.x; sE0y[buf][i] = (float)e0.y;
        sGx[buf][i]  = g.x;         sGy[buf][i]  = g.y;
    };

    // prologue: all 128 threads stage chunk 0 into buffer 0
    for (int i = tid; i < CH; i += 128) stage_one(0, i, i);
    __syncthreads();

    float y0c = inputs[0];
    float y1c = inputs[1];
    for (int c = 0; c < 3; ++c) {
        const int buf = c & 1;
        if (tid == 0) {
            // wave 0: serial recurrence over chunk c — LDS reads +
            // fire-and-forget global stores only; unroll 8 batches the
            // LDS reads ahead of the f32 chain (R8/R13 recipe).
            const int wbase = c * CH;
#pragma unroll 8
            for (int i = 0; i < CH; ++i) {
                float d0 = y0c - sGx[buf][i];
                float d1 = y1c - sGy[buf][i];
                d0 = fminf(fmaxf(d0, -50.0f), 50.0f);      // trust region
                d1 = fminf(fmaxf(d1, -400.0f), 400.0f);
                icg[wbase + i] = make_float2(y0c, y1c);    // fire-and-forget
                y0c = fmaf(sJ00[buf][i], d0, sE0x[buf][i]);        // J01 = 0
                y1c = fmaf(sJ10[buf][i], d0, fmaf(sJ11[buf][i], d1, sE0y[buf][i]));
                y0c = fminf(fmaxf(y0c, -5.0f), 1000.0f);   // physical sanity
                y1c = fminf(fmaxf(y1c, -5.0f), 5000.0f);
            }
        } else if (tid >= 64 && c + 1 < 3) {
            // wave 1: stage chunk c+1 into the other buffer, truly overlapped
            for (int i = tid - 64; i < CH; i += 64)
                stage_one((c + 1) & 1, i, (c + 1) * CH + i);
        }
        __syncthreads();
    }
}

// ---------------------------------------------------------------------------
// Parallel readout: out[t] = mlp(relu(state), p, tm)[4]
// ---------------------------------------------------------------------------
__global__ __launch_bounds__(256) void out_kernel(
    const float* __restrict__ inputs,
    const float* __restrict__ traj,
    const float* __restrict__ W1, const float* __restrict__ b1,
    const float* __restrict__ W2, const float* __restrict__ b2,
    const float* __restrict__ W3, const float* __restrict__ b3,
    float* __restrict__ out)
{
    __shared__ float sW1[4 * HID];
    __shared__ float sb1[HID];
    __shared__ float sW2T[HID * HID];
    __shared__ float sb2[HID];
    __shared__ float sw3[HID];
    for (int i = threadIdx.x; i < 4 * HID; i += 256) sW1[i] = W1[i];
    for (int i = threadIdx.x; i < HID; i += 256) {
        sb1[i] = b1[i]; sb2[i] = b2[i]; sw3[i] = W3[i * 5 + 4];
    }
    for (int idx = threadIdx.x; idx < HID * HID; idx += 256) {
        int jj = idx >> 5, ii = idx & 31;
        sW2T[idx] = W2[ii * HID + jj];
    }
    __syncthreads();

    int t = blockIdx.x * 256 + threadIdx.x;
    if (t >= T_TOTAL) return;

    float2 st = ((const float2*)traj)[t];
    float s0 = fmaxf(st.x, 0.0f);
    float s1 = fmaxf(st.y, 0.0f);
    float p  = inputs[t * 5 + 2];
    float tm = inputs[t * 5 + 3];

    float h1[HID];
#pragma unroll
    for (int jj = 0; jj < HID; ++jj) {
        float pre = fmaf(s0, sW1[jj], fmaf(s1, sW1[HID + jj],
                    fmaf(p, sW1[2 * HID + jj],
                    fmaf(tm, sW1[3 * HID + jj], sb1[jj]))));
        h1[jj] = fast_tanh_clamp(pre);
    }
    float o = b3[4];
#pragma unroll 4
    for (int jj = 0; jj < HID; ++jj) {
        float a0 = sb2[jj], a1 = 0.f, a2 = 0.f, a3 = 0.f;
#pragma unroll
        for (int ii = 0; ii < HID; ii += 4) {
            a0 = fmaf(h1[ii + 0], sW2T[jj * HID + ii + 0], a0);
            a1 = fmaf(h1[ii + 1], sW2T[jj * HID + ii + 1], a1);
            a2 = fmaf(h1[ii + 2], sW2T[jj * HID + ii + 2], a2);
            a3 = fmaf(h1[ii + 3], sW2T[jj * HID + ii + 3], a3);
        }
        o = fmaf(fast_tanh_nc((a0 + a1) + (a2 + a3)), sw3[jj], o);
    }
    out[t] = o;
}

extern "C" void kernel_launch(void* const* d_in, const int* in_sizes, int n_in,
                              void* d_out, int out_size, void* d_ws, size_t ws_size,
                              hipStream_t stream) {
    (void)in_sizes; (void)n_in; (void)out_size; (void)ws_size;
    const float* inputs = (const float*)d_in[0];
    const float* lday   = (const float*)d_in[1];
    const float* W1     = (const float*)d_in[2];
    const float* b1     = (const float*)d_in[3];
    const float* W2     = (const float*)d_in[4];
    const float* b2     = (const float*)d_in[5];
    const float* W3     = (const float*)d_in[6];
    const float* b3     = (const float*)d_in[7];
    float* out  = (float*)d_out;
    float* traj = (float*)d_ws;                 // T*2 floats = 2 MB

    // small Parareal arrays live in d_out (scratch until out_kernel, 1 MB)
    // E = 4*WIN double2 = 196608 B at offset 0; icg = WIN float2 = 24576 B
    // at offset 262144. Total 286720 <= 1 MB.
    char* scr = (char*)d_out;
    double2* E  = (double2*)scr;
    float2* icg = (float2*)(scr + 262144);

    hipLaunchKernelGGL(init_kernel, dim3((WIN + 255) / 256), dim3(256), 0, stream,
                       inputs, icg);
    for (int k = 0; k < NSWEEP - 1; ++k) {
        hipLaunchKernelGGL(sweep_kernel, dim3(WIN), dim3(64), 0, stream,
                           inputs, lday, W1, b1, W2, b2, W3, b3, traj, icg, E);
        hipLaunchKernelGGL(correct_kernel, dim3(1), dim3(128), 0, stream,
                           inputs, E, icg);
    }
    // final sweep: trajectory becomes self-consistent with corrected ICs
    hipLaunchKernelGGL(sweep_kernel, dim3(WIN), dim3(64), 0, stream,
                       inputs, lday, W1, b1, W2, b2, W3, b3, traj, icg, E);
    hipLaunchKernelGGL(out_kernel, dim3((T_TOTAL + 255) / 256), dim3(256), 0, stream,
                       inputs, traj, W1, b1, W2, b2, W3, b3, out);
}